// Round 5
// baseline (6454.779 us; speedup 1.0000x reference)
//
#include <hip/hip_runtime.h>

// GTEA T-LSTM forward — correctness-first pure-VALU implementation.
// One block per dst node (2048 x 256). All math f32; no MFMA; no workspace.
// Thread (eh = tid>>7, j = tid&127) owns hidden unit j for edges eh*16..eh*16+15.
// h/c/Eout in f32 LDS. Weights read from global (L2-resident, ~400 KB/LSTM).
// OUTPUT IS FLOAT32 (reference returns jnp.float32).

typedef unsigned short u16;
typedef unsigned int u32;

#define NDST 2048
#define HDIM 128
#define TSTEPS 16
#define DEDGE 16

__device__ __forceinline__ float sigm(float x) { return 1.f / (1.f + __expf(-x)); }

__global__ __launch_bounds__(256) void fused_simple(
    const float* __restrict__ nf, const float* __restrict__ e, const float* __restrict__ dtt,
    const float* __restrict__ W_m, const float* __restrict__ U_m, const float* __restrict__ b_m,
    const float* __restrict__ Wd_m, const float* __restrict__ bd_m,
    const float* __restrict__ W_a, const float* __restrict__ U_a, const float* __restrict__ b_a,
    const float* __restrict__ Wd_a, const float* __restrict__ bd_a,
    const float* __restrict__ attn, const float* __restrict__ eoW, const float* __restrict__ eob,
    const float* __restrict__ ndW, const float* __restrict__ ndb,
    const float* __restrict__ fcW, const float* __restrict__ fcb,
    const int* __restrict__ elen, const int* __restrict__ srci,
    float* __restrict__ out)
{
  const int node = blockIdx.x;
  const int tid = threadIdx.x;
  const int ebase = node * 32;
  const int j = tid & 127;
  const int e0 = (tid >> 7) * 16;   // this thread's edge range: e0..e0+15

  __shared__ float hL[32][128];
  __shared__ float cL[32][128];     // later reused as h_src
  __shared__ float EoutL[32][128];
  __shared__ float etL[32][16];
  __shared__ float decL[32];
  __shared__ float aval[32], zsrc[32], zs[32], redf[32], alpha_s[32];
  __shared__ float selfh[128], hagg[128], acts[128];
  __shared__ int redi[32], elen_s[32];

  if (tid < 32) elen_s[tid] = min(max(elen[ebase + tid], 1), 16);

  // ---------------- two T-LSTM passes: pass 0 = attention (a), pass 1 = message (m) ----------------
  for (int pass = 0; pass < 2; ++pass) {
    const float* W  = pass == 0 ? W_a  : W_m;
    const float* U  = pass == 0 ? U_a  : U_m;
    const float* b  = pass == 0 ? b_a  : b_m;
    const float* Wd = pass == 0 ? Wd_a : Wd_m;
    const float* bd = pass == 0 ? bd_a : bd_m;

    for (int i = tid; i < 32 * 128; i += 256) { (&hL[0][0])[i] = 0.f; (&cL[0][0])[i] = 0.f; }
    __syncthreads();   // also makes elen_s visible

    for (int t = 0; t < TSTEPS; ++t) {
      // stage e_t [32][16] and decay [32]
      for (int i = tid; i < 512; i += 256)
        (&etL[0][0])[i] = e[(size_t)(ebase + (i >> 4)) * 256 + t * 16 + (i & 15)];
      if (tid < 32)
        decL[tid] = 1.f / logf(2.718281828459045f + dtt[(size_t)(ebase + tid) * 16 + t]);
      __syncthreads();

      // gate accumulators for 16 edges (i, f, o, g, c_s-pre)
      float ai[16], af[16], ao[16], ag[16], acs[16];
      {
        float bi = b[j], bf_ = b[128 + j], bo = b[256 + j], bg_ = b[384 + j], bdj = bd[j];
#pragma unroll
        for (int q = 0; q < 16; ++q) { ai[q] = bi; af[q] = bf_; ao[q] = bo; ag[q] = bg_; acs[q] = bdj; }
      }
      // x-part: e_t @ W
      for (int d = 0; d < DEDGE; ++d) {
        float wi = W[d * 512 + j], wf = W[d * 512 + 128 + j];
        float wo = W[d * 512 + 256 + j], wg = W[d * 512 + 384 + j];
#pragma unroll
        for (int q = 0; q < 16; ++q) {
          float x = etL[e0 + q][d];
          ai[q] += x * wi; af[q] += x * wf; ao[q] += x * wo; ag[q] += x * wg;
        }
      }
      // recurrent part: h @ U  and  c @ Wd
      for (int k = 0; k < HDIM; ++k) {
        float ui = U[k * 512 + j], uf = U[k * 512 + 128 + j];
        float uo = U[k * 512 + 256 + j], ug = U[k * 512 + 384 + j];
        float wd = Wd[k * 128 + j];
#pragma unroll
        for (int q = 0; q < 16; ++q) {
          float hk = hL[e0 + q][k];
          float ck = cL[e0 + q][k];
          ai[q] += hk * ui; af[q] += hk * uf; ao[q] += hk * uo; ag[q] += hk * ug;
          acs[q] += ck * wd;
        }
      }
      __syncthreads();   // all LDS reads of h/c complete before overwrite

#pragma unroll
      for (int q = 0; q < 16; ++q) {
        const int er = e0 + q;
        float cs = tanhf(acs[q]);
        float cstar = cL[er][j] - cs + cs * decL[er];   // c - c_s + c_s * g(dt)
        float iv = sigm(ai[q]), fv = sigm(af[q]), ov = sigm(ao[q]);
        float cn = fv * cstar + iv * tanhf(ag[q]);
        float hn = ov * tanhf(cn);
        cL[er][j] = cn;
        hL[er][j] = hn;
        if (elen_s[er] == t + 1) EoutL[er][j] = hn;     // h at step e_len-1
      }
      __syncthreads();
    }

    if (pass == 0) {  // attention logit per edge: a = leaky_relu(a_h @ attn_w)
      if (tid < 32) {
        float s = 0.f;
        for (int k = 0; k < HDIM; ++k) s += EoutL[tid][k] * attn[k];
        aval[tid] = s > 0.f ? s : 0.01f * s;
      }
      __syncthreads();
    }
  }
  // EoutL now holds e_out (message LSTM). hL/cL free.

  // ---------------- stage h_src into cL; self features ----------------
  for (int i = tid; i < 32 * 128; i += 256) {
    int er = i >> 7, k = i & 127;
    cL[er][k] = nf[(size_t)srci[ebase + er] * 128 + k];
  }
  if (tid < 128) selfh[tid] = nf[(size_t)node * 128 + tid];
  __syncthreads();

  // ---------------- edge message: M[e][j] = relu([h_src | e_out] @ eoW + eob), into hL ----------------
  {
    float accm[16];
    float bj = eob[j];
#pragma unroll
    for (int q = 0; q < 16; ++q) accm[q] = bj;
    for (int k = 0; k < HDIM; ++k) {
      float w1 = eoW[k * 128 + j];
#pragma unroll
      for (int q = 0; q < 16; ++q) accm[q] += cL[e0 + q][k] * w1;
    }
    for (int k = 0; k < HDIM; ++k) {
      float w2 = eoW[(128 + k) * 128 + j];
#pragma unroll
      for (int q = 0; q < 16; ++q) accm[q] += EoutL[e0 + q][k] * w2;
    }
#pragma unroll
    for (int q = 0; q < 16; ++q) hL[e0 + q][j] = fmaxf(accm[q], 0.f);
  }
  __syncthreads();

  // ---------------- sparsemax over aval[32] ----------------
  if (tid < 32) {
    float mx = -1e30f;
    for (int jj = 0; jj < 32; ++jj) mx = fmaxf(mx, aval[jj]);
    float z = aval[tid] - mx;
    zsrc[tid] = z;
    int rank = 0;
    for (int jj = 0; jj < 32; ++jj) {
      float zj = aval[jj] - mx;
      rank += (zj > z) || (zj == z && jj < tid);
    }
    zs[rank] = z;   // descending sort via rank scatter
  }
  __syncthreads();
  if (tid < 32) {
    float cum = 0.f;
    for (int s = 0; s <= tid; ++s) cum += zs[s];
    float zst = zs[tid];
    bool isg = (1.f + (float)(tid + 1) * zst) > cum;
    redf[tid] = isg ? zst : 0.f;
    redi[tid] = isg ? (tid + 1) : 0;
  }
  __syncthreads();
  if (tid < 32) {
    int kk = 0; float ss = 0.f;
    for (int jj = 0; jj < 32; ++jj) { kk = max(kk, redi[jj]); ss += redf[jj]; }
    float tau = (ss - 1.f) / (float)kk;
    alpha_s[tid] = fmaxf(0.f, zsrc[tid] - tau);
  }
  __syncthreads();

  // ---------------- h_agg = sum_d alpha_d * M[d] - self_h_tmp ----------------
  if (tid < 128) {
    float s = 0.f;
    for (int d = 0; d < 32; ++d) s += alpha_s[d] * hL[d][tid];
    float st = eob[tid];
    for (int k = 0; k < HDIM; ++k) st += selfh[k] * eoW[k * 128 + tid];
    hagg[tid] = s - st;
  }
  __syncthreads();

  // ---------------- node MLP + fc ----------------
  if (tid < 128) {
    float Av = ndb[tid];
    for (int k = 0; k < HDIM; ++k) Av += selfh[k] * ndW[k * 128 + tid];
    for (int k = 0; k < HDIM; ++k) Av += hagg[k] * ndW[(128 + k) * 128 + tid];
    acts[tid] = fmaxf(Av, 0.f);
  }
  __syncthreads();
  if (tid < 10) {
    float o = fcb[tid];
    for (int k = 0; k < HDIM; ++k) o += acts[k] * fcW[k * 10 + tid];
    out[node * 10 + tid] = o;   // FLOAT32 output
  }
}

extern "C" void kernel_launch(void* const* d_in, const int* in_sizes, int n_in,
                              void* d_out, int out_size, void* d_ws, size_t ws_size,
                              hipStream_t stream)
{
  const float* nf   = (const float*)d_in[0];
  const float* e    = (const float*)d_in[1];
  const float* dtt  = (const float*)d_in[2];
  const float* W_m  = (const float*)d_in[3];
  const float* U_m  = (const float*)d_in[4];
  const float* b_m  = (const float*)d_in[5];
  const float* Wd_m = (const float*)d_in[6];
  const float* bd_m = (const float*)d_in[7];
  const float* W_a  = (const float*)d_in[8];
  const float* U_a  = (const float*)d_in[9];
  const float* b_a  = (const float*)d_in[10];
  const float* Wd_a = (const float*)d_in[11];
  const float* bd_a = (const float*)d_in[12];
  const float* attn = (const float*)d_in[13];
  const float* eoW  = (const float*)d_in[14];
  const float* eob  = (const float*)d_in[15];
  const float* ndW  = (const float*)d_in[16];
  const float* ndb  = (const float*)d_in[17];
  const float* fcW  = (const float*)d_in[18];
  const float* fcb  = (const float*)d_in[19];
  const int* elen = (const int*)d_in[20];
  const int* srci = (const int*)d_in[21];

  fused_simple<<<NDST, 256, 0, stream>>>(nf, e, dtt,
                                         W_m, U_m, b_m, Wd_m, bd_m,
                                         W_a, U_a, b_a, Wd_a, bd_a,
                                         attn, eoW, eob, ndW, ndb, fcW, fcb,
                                         elen, srci, (float*)d_out);
}

// Round 6
// 1105.739 us; speedup vs baseline: 5.8375x; 5.8375x over previous
//
#include <hip/hip_runtime.h>

// GTEA T-LSTM forward. Inputs f32, OUTPUT f32. MFMA bf16 compute.
//   prep_kernel:  f32 weights -> packed bf16: UWt[512][160] (U k=0..127, W k=128..143, 0-pad),
//                 WdT[128][128], eoWt[128][256].  (ws: 459 KB)
//   fused_kernel: one block per dst node (2048 x 256).
//     a-LSTM(32 edges) -> aval ; m-LSTM -> Eout ; edge GEMM -> M ;
//     sparsemax + aggregate + node MLP + fc -> out. State in LDS/regs, exact c in f32 regs.

typedef unsigned short u16;
typedef unsigned int u32;
typedef float f32x4 __attribute__((ext_vector_type(4)));
typedef short bf16x8 __attribute__((ext_vector_type(8)));

#define NDST 2048

__device__ __forceinline__ float bf2f(u16 u) {
  union { u32 i; float f; } v; v.i = ((u32)u) << 16; return v.f;
}
__device__ __forceinline__ u16 f2bf(float f) {
  u32 x = __builtin_bit_cast(u32, f);
  u32 r = x + 0x7fffu + ((x >> 16) & 1u);
  return (u16)(r >> 16);
}
__device__ __forceinline__ bf16x8 ldb8(const u16* p) {
  return *reinterpret_cast<const bf16x8*>(p);
}
__device__ __forceinline__ f32x4 mfma16(bf16x8 a, bf16x8 b, f32x4 c) {
  return __builtin_amdgcn_mfma_f32_16x16x32_bf16(a, b, c, 0, 0, 0);
}
__device__ __forceinline__ float rcp_(float x) { return __builtin_amdgcn_rcpf(x); }
__device__ __forceinline__ float sigm(float x) { return rcp_(1.f + __expf(-x)); }
__device__ __forceinline__ float tanh_(float x) { return 2.f * rcp_(1.f + __expf(-2.f * x)) - 1.f; }

// ---------------- weight prep: f32 -> packed bf16 ----------------
__global__ __launch_bounds__(256) void prep_kernel(
    const float* __restrict__ U_m, const float* __restrict__ W_m,
    const float* __restrict__ U_a, const float* __restrict__ W_a,
    const float* __restrict__ Wd_m, const float* __restrict__ Wd_a,
    const float* __restrict__ eoW,
    u16* __restrict__ UWt_m, u16* __restrict__ UWt_a,
    u16* __restrict__ WdT_m, u16* __restrict__ WdT_a, u16* __restrict__ eoWt)
{
  int idx = blockIdx.x * 256 + threadIdx.x;
  if (idx < 163840) {                          // UWt: [512 cols][160 k]
    int s = idx >= 81920 ? 1 : 0;
    int i = idx - s * 81920;
    int j = i / 160, k = i % 160;
    const float* U = s ? U_a : U_m;
    const float* W = s ? W_a : W_m;
    float v = 0.f;
    if (k < 128) v = U[k * 512 + j];
    else if (k < 144) v = W[(k - 128) * 512 + j];
    (s ? UWt_a : UWt_m)[j * 160 + k] = f2bf(v);
  } else if (idx < 196608) {                   // WdT: [128 cols][128 k]
    int i = idx - 163840;
    int s = i >= 16384 ? 1 : 0;
    i -= s * 16384;
    int j = i >> 7, k = i & 127;
    (s ? WdT_a : WdT_m)[j * 128 + k] = f2bf((s ? Wd_a : Wd_m)[k * 128 + j]);
  } else if (idx < 229376) {                   // eoWt: [128 cols][256 k]
    int i = idx - 196608;
    int j = i >> 8, k = i & 255;
    eoWt[j * 256 + k] = f2bf(eoW[k * 128 + j]);
  }
}

// ---------------- one T-LSTM pass over 32 edges (whole block) ----------------
// A: stride 168 u16; cols 0..127 h(bf16), 128..143 e_t(bf16), 144..159 zero.
// C: stride 136 u16; c as bf16 (operand of c@Wd). Exact c stays in f32 regs.
// Eout: stride 136; h at t = elen-1 per edge.
__device__ __forceinline__ void lstm_pass(
    const float* __restrict__ e, const float* __restrict__ dtt, int ebase,
    const u16* __restrict__ UWt, const u16* __restrict__ WdT,
    const float* __restrict__ bg, const float* __restrict__ bdp,
    const int* elen_s, int tmax,
    u16* A, u16* C, u16* Eout, float* dec_s, int tid)
{
  const int w = tid >> 6;
  const int lane = tid & 63;
  const int l15 = lane & 15;
  const int lhi = lane >> 4;

  for (int i = tid; i < 32 * 168; i += 256) A[i] = 0;
  for (int i = tid; i < 32 * 136; i += 256) C[i] = 0;
  __syncthreads();
  { // stage e_t for t=0 (f32 -> bf16)
    int row = tid >> 3, p = tid & 7;
    const float* ep = e + (size_t)(ebase + row) * 256 + p * 2;
    u32 v = ((u32)f2bf(ep[1]) << 16) | (u32)f2bf(ep[0]);
    *reinterpret_cast<u32*>(&A[row * 168 + 128 + p * 2]) = v;
  }
  float bgr[8];
#pragma unroll
  for (int n = 0; n < 8; ++n)
    bgr[n] = bg[(n >> 1) * 128 + w * 32 + (n & 1) * 16 + l15];
  float bdr[2];
#pragma unroll
  for (int n = 0; n < 2; ++n) bdr[n] = bdp[w * 32 + n * 16 + l15];

  float cst[2][2][4];
#pragma unroll
  for (int m = 0; m < 2; ++m)
#pragma unroll
    for (int js = 0; js < 2; ++js)
#pragma unroll
      for (int r = 0; r < 4; ++r) cst[m][js][r] = 0.f;
  __syncthreads();

  for (int t = 0; t < tmax; ++t) {
    if (tid < 32)
      dec_s[tid] = 1.f / logf(2.7182818284590452f + dtt[(size_t)(ebase + tid) * 16 + t]);

    f32x4 acc[2][8];
#pragma unroll
    for (int m = 0; m < 2; ++m)
#pragma unroll
      for (int n = 0; n < 8; ++n) {
        float b = bgr[n];
        f32x4 tmp = {b, b, b, b};
        acc[m][n] = tmp;
      }
    f32x4 accs[2][2];
#pragma unroll
    for (int m = 0; m < 2; ++m)
#pragma unroll
      for (int n = 0; n < 2; ++n) {
        float b = bdr[n];
        f32x4 tmp = {b, b, b, b};
        accs[m][n] = tmp;
      }
#pragma unroll
    for (int ks = 0; ks < 5; ++ks) {
      bf16x8 a0 = ldb8(&A[l15 * 168 + ks * 32 + lhi * 8]);
      bf16x8 a1 = ldb8(&A[(16 + l15) * 168 + ks * 32 + lhi * 8]);
#pragma unroll
      for (int n = 0; n < 8; ++n) {
        bf16x8 bu = ldb8(UWt + (size_t)((n >> 1) * 128 + w * 32 + (n & 1) * 16 + l15) * 160
                         + ks * 32 + lhi * 8);
        acc[0][n] = mfma16(a0, bu, acc[0][n]);
        acc[1][n] = mfma16(a1, bu, acc[1][n]);
      }
    }
#pragma unroll
    for (int ks = 0; ks < 4; ++ks) {
      bf16x8 c0 = ldb8(&C[l15 * 136 + ks * 32 + lhi * 8]);
      bf16x8 c1 = ldb8(&C[(16 + l15) * 136 + ks * 32 + lhi * 8]);
#pragma unroll
      for (int n = 0; n < 2; ++n) {
        bf16x8 bd = ldb8(WdT + (size_t)(w * 32 + n * 16 + l15) * 128 + ks * 32 + lhi * 8);
        accs[0][n] = mfma16(c0, bd, accs[0][n]);
        accs[1][n] = mfma16(c1, bd, accs[1][n]);
      }
    }
    __syncthreads();

#pragma unroll
    for (int m = 0; m < 2; ++m)
#pragma unroll
      for (int js = 0; js < 2; ++js)
#pragma unroll
        for (int r = 0; r < 4; ++r) {
          const int row = m * 16 + lhi * 4 + r;
          float iv = sigm(acc[m][js][r]);
          float fv = sigm(acc[m][2 + js][r]);
          float ov = sigm(acc[m][4 + js][r]);
          float gv = tanh_(acc[m][6 + js][r]);
          float cs = tanh_(accs[m][js][r]);
          float dec = dec_s[row];
          float co = cst[m][js][r];
          float cstar = co + cs * (dec - 1.f);   // c - c_s + c_s*dec
          float cn = fv * cstar + iv * gv;
          float hn = ov * tanh_(cn);
          cst[m][js][r] = cn;
          const int j = w * 32 + js * 16 + l15;
          u16 hb = f2bf(hn);
          A[row * 168 + j] = hb;
          C[row * 136 + j] = f2bf(cn);
          if (elen_s[row] == t + 1) Eout[row * 136 + j] = hb;
        }
    if (t + 1 < tmax) { // stage next e_t
      int row = tid >> 3, p = tid & 7;
      const float* ep = e + (size_t)(ebase + row) * 256 + (t + 1) * 16 + p * 2;
      u32 v = ((u32)f2bf(ep[1]) << 16) | (u32)f2bf(ep[0]);
      *reinterpret_cast<u32*>(&A[row * 168 + 128 + p * 2]) = v;
    }
    __syncthreads();
  }
}

// ---------------- fused per-node kernel ----------------
__global__ __launch_bounds__(256) void fused_kernel(
    const float* __restrict__ nf, const float* __restrict__ e, const float* __restrict__ dtt,
    const float* __restrict__ b_m, const float* __restrict__ bd_m,
    const float* __restrict__ b_a, const float* __restrict__ bd_a,
    const float* __restrict__ attn, const float* __restrict__ eoW, const float* __restrict__ eob,
    const float* __restrict__ ndW, const float* __restrict__ ndb,
    const float* __restrict__ fcW, const float* __restrict__ fcb,
    const int* __restrict__ elen, const int* __restrict__ srci,
    const u16* __restrict__ UWt_m, const u16* __restrict__ UWt_a,
    const u16* __restrict__ WdT_m, const u16* __restrict__ WdT_a,
    const u16* __restrict__ eoWt, float* __restrict__ out)
{
  const int node = blockIdx.x;
  const int tid = threadIdx.x;
  const int ebase = node * 32;
  const int w = tid >> 6, lane = tid & 63, l15 = lane & 15, lhi = lane >> 4;

  __shared__ __align__(16) u16 buf[32 * 168 + 32 * 136]; // A(168)+C(136); reused as A2(264)
  __shared__ __align__(16) u16 Eout[32 * 136];
  __shared__ __align__(16) u16 Msh[32 * 136];
  __shared__ float dec_s[32];
  __shared__ float selfh[128], aval[32], zsrc[32], zs[32], redf[32], alpha_s[32];
  __shared__ float hagg[128], acts[128];
  __shared__ int redi[32], elen_s[32], tmax_s;

  u16* A = buf;
  u16* C = buf + 32 * 168;

  if (tid < 32) elen_s[tid] = min(max(elen[ebase + tid], 1), 16);
  __syncthreads();
  if (tid == 0) {
    int mx = 1;
    for (int i = 0; i < 32; ++i) mx = max(mx, elen_s[i]);
    tmax_s = mx;
  }
  __syncthreads();
  const int tmax = tmax_s;

  // ---- attention LSTM -> per-edge logit ----
  lstm_pass(e, dtt, ebase, UWt_a, WdT_a, b_a, bd_a, elen_s, tmax, A, C, Eout, dec_s, tid);
  if (tid < 128) {
    const int el = tid >> 2, l4 = tid & 3;
    float s = 0.f;
    for (int k = 0; k < 32; ++k)
      s += bf2f(Eout[el * 136 + l4 * 32 + k]) * attn[l4 * 32 + k];
    s += __shfl_xor(s, 1);
    s += __shfl_xor(s, 2);
    if (l4 == 0) aval[el] = s > 0.f ? s : 0.01f * s;
  }
  __syncthreads();

  // ---- message LSTM -> Eout = e_out ----
  lstm_pass(e, dtt, ebase, UWt_m, WdT_m, b_m, bd_m, elen_s, tmax, A, C, Eout, dec_s, tid);

  // ---- edge GEMM: M = relu([h_src | e_out] @ edge_out_W + b) ----
  { // build A2[32][256] stride 264 (reuses buf; A/C contents dead)
    const int row = tid >> 3, p = tid & 7;
    const int src = srci[ebase + row];
    const float* ph = nf + (size_t)src * 128 + p * 16;
    float vv[16];
#pragma unroll
    for (int i = 0; i < 4; ++i)
      *reinterpret_cast<float4*>(&vv[i * 4]) =
          *reinterpret_cast<const float4*>(ph + i * 4);
#pragma unroll
    for (int i = 0; i < 16; ++i) buf[row * 264 + p * 16 + i] = f2bf(vv[i]);
    *reinterpret_cast<uint4*>(&buf[row * 264 + 128 + p * 16]) =
        *reinterpret_cast<const uint4*>(&Eout[row * 136 + p * 16]);
    *reinterpret_cast<uint4*>(&buf[row * 264 + 128 + p * 16 + 8]) =
        *reinterpret_cast<const uint4*>(&Eout[row * 136 + p * 16 + 8]);
  }
  if (tid < 128) selfh[tid] = nf[(size_t)node * 128 + tid];
  __syncthreads();
  {
    f32x4 eacc[2][2];
    const int j0 = w * 32 + l15, j1 = w * 32 + 16 + l15;
    {
      float v0 = eob[j0], v1 = eob[j1];
      f32x4 t0 = {v0, v0, v0, v0}, t1 = {v1, v1, v1, v1};
      eacc[0][0] = t0; eacc[1][0] = t0;
      eacc[0][1] = t1; eacc[1][1] = t1;
    }
#pragma unroll
    for (int ks = 0; ks < 8; ++ks) {
      bf16x8 a0 = ldb8(&buf[l15 * 264 + ks * 32 + lhi * 8]);
      bf16x8 a1 = ldb8(&buf[(16 + l15) * 264 + ks * 32 + lhi * 8]);
      bf16x8 b0 = ldb8(eoWt + (size_t)j0 * 256 + ks * 32 + lhi * 8);
      bf16x8 b1 = ldb8(eoWt + (size_t)j1 * 256 + ks * 32 + lhi * 8);
      eacc[0][0] = mfma16(a0, b0, eacc[0][0]);
      eacc[1][0] = mfma16(a1, b0, eacc[1][0]);
      eacc[0][1] = mfma16(a0, b1, eacc[0][1]);
      eacc[1][1] = mfma16(a1, b1, eacc[1][1]);
    }
#pragma unroll
    for (int m = 0; m < 2; ++m)
#pragma unroll
      for (int n = 0; n < 2; ++n)
#pragma unroll
        for (int r = 0; r < 4; ++r) {
          const int row = m * 16 + lhi * 4 + r;
          const int j = w * 32 + n * 16 + l15;
          Msh[row * 136 + j] = f2bf(fmaxf(eacc[m][n][r], 0.f));
        }
  }
  __syncthreads();

  // ---- sparsemax over aval[32] ----
  if (tid < 32) {
    float mx = -1e30f;
    for (int jj = 0; jj < 32; ++jj) mx = fmaxf(mx, aval[jj]);
    float z = aval[tid] - mx;
    zsrc[tid] = z;
    int rank = 0;
    for (int jj = 0; jj < 32; ++jj) {
      float zj = aval[jj] - mx;
      rank += (zj > z) || (zj == z && jj < tid);
    }
    zs[rank] = z;
  }
  __syncthreads();
  if (tid < 32) {
    float cum = 0.f;
    for (int s = 0; s <= tid; ++s) cum += zs[s];
    float zst = zs[tid];
    bool isg = (1.f + (float)(tid + 1) * zst) > cum;
    redf[tid] = isg ? zst : 0.f;
    redi[tid] = isg ? (tid + 1) : 0;
  }
  __syncthreads();
  if (tid < 32) {
    int kk = 0; float ss = 0.f;
    for (int jj = 0; jj < 32; ++jj) { kk = max(kk, redi[jj]); ss += redf[jj]; }
    float tau = (ss - 1.f) / (float)kk;
    alpha_s[tid] = fmaxf(0.f, zsrc[tid] - tau);
  }
  __syncthreads();

  // ---- h_agg = sum_d alpha_d * M[d] - self_h_tmp ----
  if (tid < 128) {
    float s = 0.f;
    for (int d = 0; d < 32; ++d) s += alpha_s[d] * bf2f(Msh[d * 136 + tid]);
    float st = eob[tid];
    for (int k2 = 0; k2 < 128; ++k2) st += selfh[k2] * eoW[k2 * 128 + tid];
    hagg[tid] = s - st;
  }
  __syncthreads();
  if (tid < 128) {
    float Av = ndb[tid];
    for (int k2 = 0; k2 < 128; ++k2) Av += selfh[k2] * ndW[k2 * 128 + tid];
    for (int k2 = 0; k2 < 128; ++k2) Av += hagg[k2] * ndW[(128 + k2) * 128 + tid];
    acts[tid] = fmaxf(Av, 0.f);
  }
  __syncthreads();
  if (tid < 10) {
    float o = fcb[tid];
    for (int k = 0; k < 128; ++k) o += acts[k] * fcW[k * 10 + tid];
    out[node * 10 + tid] = o;   // FLOAT32 output
  }
}

extern "C" void kernel_launch(void* const* d_in, const int* in_sizes, int n_in,
                              void* d_out, int out_size, void* d_ws, size_t ws_size,
                              hipStream_t stream)
{
  const float* nf   = (const float*)d_in[0];
  const float* e    = (const float*)d_in[1];
  const float* dtt  = (const float*)d_in[2];
  const float* W_m  = (const float*)d_in[3];
  const float* U_m  = (const float*)d_in[4];
  const float* b_m  = (const float*)d_in[5];
  const float* Wd_m = (const float*)d_in[6];
  const float* bd_m = (const float*)d_in[7];
  const float* W_a  = (const float*)d_in[8];
  const float* U_a  = (const float*)d_in[9];
  const float* b_a  = (const float*)d_in[10];
  const float* Wd_a = (const float*)d_in[11];
  const float* bd_a = (const float*)d_in[12];
  const float* attn = (const float*)d_in[13];
  const float* eoW  = (const float*)d_in[14];
  const float* eob  = (const float*)d_in[15];
  const float* ndW  = (const float*)d_in[16];
  const float* ndb  = (const float*)d_in[17];
  const float* fcW  = (const float*)d_in[18];
  const float* fcb  = (const float*)d_in[19];
  const int* elen = (const int*)d_in[20];
  const int* srci = (const int*)d_in[21];

  char* ws = (char*)d_ws;
  u16* UWt_m = (u16*)(ws + 0);
  u16* UWt_a = (u16*)(ws + 163840);
  u16* WdT_m = (u16*)(ws + 327680);
  u16* WdT_a = (u16*)(ws + 360448);
  u16* eoWt  = (u16*)(ws + 393216);   // ends at 458752 bytes

  prep_kernel<<<896, 256, 0, stream>>>(U_m, W_m, U_a, W_a, Wd_m, Wd_a, eoW,
                                       UWt_m, UWt_a, WdT_m, WdT_a, eoWt);
  fused_kernel<<<NDST, 256, 0, stream>>>(nf, e, dtt, b_m, bd_m, b_a, bd_a,
                                         attn, eoW, eob, ndW, ndb, fcW, fcb,
                                         elen, srci, UWt_m, UWt_a, WdT_m, WdT_a,
                                         eoWt, (float*)d_out);
}

// Round 7
// 1051.619 us; speedup vs baseline: 6.1379x; 1.0515x over previous
//
#include <hip/hip_runtime.h>

// GTEA T-LSTM forward. Inputs f32, OUTPUT f32. MFMA bf16 compute.
// Pipeline:
//   prep:   f32 weights -> packed bf16 UWt[512][160], WdT[128][128], eoWt[128][256]
//   sort:   counting-sort edge ids by e_len (hist/scan/scatter) -> perm
//           (perm order is nondeterministic across runs, but outputs are bitwise
//            independent of row grouping: MFMA rows don't interact.)
//   lstm:   4096 blocks x 256: block (sel, g) runs LSTM 'sel' on sorted edges
//           g*32..g*32+31; loop bound = block max e_len (~8.9 avg after sort vs 15.6).
//           sel=0 (message) writes e_out[E][128] bf16; sel=1 (attention) reduces
//           h @ attn_w -> aval[E] f32 in-kernel.
//   node:   per dst node: edge GEMM (MFMA) + sparsemax + aggregate + MLP + fc.
// ws: 459KB weights + 16MB e_out + 256KB aval + 256KB perm + 128B counters ~= 17.8MB

typedef unsigned short u16;
typedef unsigned int u32;
typedef float f32x4 __attribute__((ext_vector_type(4)));
typedef short bf16x8 __attribute__((ext_vector_type(8)));

#define NDST 2048
#define EDGES 65536

__device__ __forceinline__ float bf2f(u16 u) {
  union { u32 i; float f; } v; v.i = ((u32)u) << 16; return v.f;
}
__device__ __forceinline__ u16 f2bf(float f) {
  u32 x = __builtin_bit_cast(u32, f);
  u32 r = x + 0x7fffu + ((x >> 16) & 1u);
  return (u16)(r >> 16);
}
__device__ __forceinline__ bf16x8 ldb8(const u16* p) {
  return *reinterpret_cast<const bf16x8*>(p);
}
__device__ __forceinline__ f32x4 mfma16(bf16x8 a, bf16x8 b, f32x4 c) {
  return __builtin_amdgcn_mfma_f32_16x16x32_bf16(a, b, c, 0, 0, 0);
}
__device__ __forceinline__ float rcp_(float x) { return __builtin_amdgcn_rcpf(x); }
__device__ __forceinline__ float sigm(float x) { return rcp_(1.f + __expf(-x)); }
__device__ __forceinline__ float tanh_(float x) { return 2.f * rcp_(1.f + __expf(-2.f * x)) - 1.f; }

// ---------------- weight prep: f32 -> packed bf16 ----------------
__global__ __launch_bounds__(256) void prep_kernel(
    const float* __restrict__ U_m, const float* __restrict__ W_m,
    const float* __restrict__ U_a, const float* __restrict__ W_a,
    const float* __restrict__ Wd_m, const float* __restrict__ Wd_a,
    const float* __restrict__ eoW,
    u16* __restrict__ UWt_m, u16* __restrict__ UWt_a,
    u16* __restrict__ WdT_m, u16* __restrict__ WdT_a, u16* __restrict__ eoWt)
{
  int idx = blockIdx.x * 256 + threadIdx.x;
  if (idx < 163840) {                          // UWt: [512 cols][160 k]
    int s = idx >= 81920 ? 1 : 0;
    int i = idx - s * 81920;
    int j = i / 160, k = i % 160;
    const float* U = s ? U_a : U_m;
    const float* W = s ? W_a : W_m;
    float v = 0.f;
    if (k < 128) v = U[k * 512 + j];
    else if (k < 144) v = W[(k - 128) * 512 + j];
    (s ? UWt_a : UWt_m)[j * 160 + k] = f2bf(v);
  } else if (idx < 196608) {                   // WdT: [128 cols][128 k]
    int i = idx - 163840;
    int s = i >= 16384 ? 1 : 0;
    i -= s * 16384;
    int j = i >> 7, k = i & 127;
    (s ? WdT_a : WdT_m)[j * 128 + k] = f2bf((s ? Wd_a : Wd_m)[k * 128 + j]);
  } else if (idx < 229376) {                   // eoWt: [128 cols][256 k]
    int i = idx - 196608;
    int j = i >> 8, k = i & 255;
    eoWt[j * 256 + k] = f2bf(eoW[k * 128 + j]);
  }
}

// ---------------- counting sort by e_len ----------------
__global__ void hist_kernel(const int* __restrict__ elen, int* __restrict__ cnt) {
  int e = blockIdx.x * 256 + threadIdx.x;
  int b = min(max(elen[e] - 1, 0), 15);
  atomicAdd(&cnt[b], 1);
}
__global__ void scan_kernel(const int* __restrict__ cnt, int* __restrict__ coff) {
  if (threadIdx.x == 0 && blockIdx.x == 0) {
    int a = 0;
    for (int i = 0; i < 16; ++i) { coff[i] = a; a += cnt[i]; }
  }
}
__global__ void scatter_kernel(const int* __restrict__ elen, int* __restrict__ coff,
                               int* __restrict__ perm) {
  int e = blockIdx.x * 256 + threadIdx.x;
  int b = min(max(elen[e] - 1, 0), 15);
  int pos = atomicAdd(&coff[b], 1);
  perm[pos] = e;
}

// ---------------- T-LSTM over 32 sorted edges ----------------
// A: stride 168 u16; cols 0..127 h(bf16), 128..143 e_t, 144..159 zero.
// C: stride 136 u16; c as bf16 (operand of c@Wd). Exact c in f32 regs.
__global__ __launch_bounds__(256) void lstm_kernel(
    const float* __restrict__ e, const float* __restrict__ dtt,
    const float* __restrict__ b_m, const float* __restrict__ bd_m,
    const float* __restrict__ b_a, const float* __restrict__ bd_a,
    const float* __restrict__ attn,
    const int* __restrict__ elen, const int* __restrict__ perm,
    const u16* __restrict__ UWt_m, const u16* __restrict__ UWt_a,
    const u16* __restrict__ WdT_m, const u16* __restrict__ WdT_a,
    u16* __restrict__ e_out, float* __restrict__ aval_g)
{
  const int bid = blockIdx.x;
  const int sel = bid >> 11;             // 0 = message LSTM, 1 = attention LSTM
  const int edge0 = (bid & 2047) * 32;
  const u16* UWt = sel ? UWt_a : UWt_m;
  const u16* WdT = sel ? WdT_a : WdT_m;
  const float* bg  = sel ? b_a  : b_m;
  const float* bdp = sel ? bd_a : bd_m;

  __shared__ __align__(16) u16 A[32 * 168];
  __shared__ __align__(16) u16 C[32 * 136];
  __shared__ __align__(16) u16 Eo[32 * 136];
  __shared__ float dec_s[32];
  __shared__ int rowedge[32], elen_s[32], tmax_s;

  const int tid = threadIdx.x;
  const int w = tid >> 6, lane = tid & 63, l15 = lane & 15, lhi = lane >> 4;

  if (tid < 32) {
    int ed = perm[edge0 + tid];
    rowedge[tid] = ed;
    elen_s[tid] = min(max(elen[ed], 1), 16);
  }
  for (int i = tid; i < 32 * 168; i += 256) A[i] = 0;
  for (int i = tid; i < 32 * 136; i += 256) C[i] = 0;
  __syncthreads();
  if (tid == 0) {
    int mx = 1;
    for (int i = 0; i < 32; ++i) mx = max(mx, elen_s[i]);
    tmax_s = mx;
  }
  { // stage e_t for t=0
    int row = tid >> 3, p = tid & 7;
    const float* ep = e + (size_t)rowedge[row] * 256 + p * 2;
    u32 v = ((u32)f2bf(ep[1]) << 16) | (u32)f2bf(ep[0]);
    *reinterpret_cast<u32*>(&A[row * 168 + 128 + p * 2]) = v;
  }
  float bgr[8];
#pragma unroll
  for (int n = 0; n < 8; ++n)
    bgr[n] = bg[(n >> 1) * 128 + w * 32 + (n & 1) * 16 + l15];
  float bdr[2];
#pragma unroll
  for (int n = 0; n < 2; ++n) bdr[n] = bdp[w * 32 + n * 16 + l15];

  float cst[2][2][4];
#pragma unroll
  for (int m = 0; m < 2; ++m)
#pragma unroll
    for (int js = 0; js < 2; ++js)
#pragma unroll
      for (int r = 0; r < 4; ++r) cst[m][js][r] = 0.f;
  __syncthreads();
  const int tmax = tmax_s;

  for (int t = 0; t < tmax; ++t) {
    if (tid < 32)
      dec_s[tid] = 1.f / logf(2.7182818284590452f + dtt[(size_t)rowedge[tid] * 16 + t]);

    f32x4 acc[2][8];
#pragma unroll
    for (int m = 0; m < 2; ++m)
#pragma unroll
      for (int n = 0; n < 8; ++n) {
        float b = bgr[n];
        f32x4 tmp = {b, b, b, b};
        acc[m][n] = tmp;
      }
    f32x4 accs[2][2];
#pragma unroll
    for (int m = 0; m < 2; ++m)
#pragma unroll
      for (int n = 0; n < 2; ++n) {
        float b = bdr[n];
        f32x4 tmp = {b, b, b, b};
        accs[m][n] = tmp;
      }
#pragma unroll
    for (int ks = 0; ks < 5; ++ks) {
      bf16x8 a0 = ldb8(&A[l15 * 168 + ks * 32 + lhi * 8]);
      bf16x8 a1 = ldb8(&A[(16 + l15) * 168 + ks * 32 + lhi * 8]);
#pragma unroll
      for (int n = 0; n < 8; ++n) {
        bf16x8 bu = ldb8(UWt + (size_t)((n >> 1) * 128 + w * 32 + (n & 1) * 16 + l15) * 160
                         + ks * 32 + lhi * 8);
        acc[0][n] = mfma16(a0, bu, acc[0][n]);
        acc[1][n] = mfma16(a1, bu, acc[1][n]);
      }
    }
#pragma unroll
    for (int ks = 0; ks < 4; ++ks) {
      bf16x8 c0 = ldb8(&C[l15 * 136 + ks * 32 + lhi * 8]);
      bf16x8 c1 = ldb8(&C[(16 + l15) * 136 + ks * 32 + lhi * 8]);
#pragma unroll
      for (int n = 0; n < 2; ++n) {
        bf16x8 bd = ldb8(WdT + (size_t)(w * 32 + n * 16 + l15) * 128 + ks * 32 + lhi * 8);
        accs[0][n] = mfma16(c0, bd, accs[0][n]);
        accs[1][n] = mfma16(c1, bd, accs[1][n]);
      }
    }
    __syncthreads();

#pragma unroll
    for (int m = 0; m < 2; ++m)
#pragma unroll
      for (int js = 0; js < 2; ++js)
#pragma unroll
        for (int r = 0; r < 4; ++r) {
          const int row = m * 16 + lhi * 4 + r;
          float iv = sigm(acc[m][js][r]);
          float fv = sigm(acc[m][2 + js][r]);
          float ov = sigm(acc[m][4 + js][r]);
          float gv = tanh_(acc[m][6 + js][r]);
          float cs = tanh_(accs[m][js][r]);
          float dec = dec_s[row];
          float co = cst[m][js][r];
          float cstar = co + cs * (dec - 1.f);   // c - c_s + c_s*dec
          float cn = fv * cstar + iv * gv;
          float hn = ov * tanh_(cn);
          cst[m][js][r] = cn;
          const int j = w * 32 + js * 16 + l15;
          u16 hb = f2bf(hn);
          A[row * 168 + j] = hb;
          C[row * 136 + j] = f2bf(cn);
          if (elen_s[row] == t + 1) Eo[row * 136 + j] = hb;
        }
    if (t + 1 < tmax) { // stage next e_t
      int row = tid >> 3, p = tid & 7;
      const float* ep = e + (size_t)rowedge[row] * 256 + (t + 1) * 16 + p * 2;
      u32 v = ((u32)f2bf(ep[1]) << 16) | (u32)f2bf(ep[0]);
      *reinterpret_cast<u32*>(&A[row * 168 + 128 + p * 2]) = v;
    }
    __syncthreads();
  }

  if (sel) {   // attention logit: leaky_relu(h . attn_w)
    if (tid < 32) {
      float s = 0.f;
      for (int k = 0; k < 128; ++k) s += bf2f(Eo[tid * 136 + k]) * attn[k];
      aval_g[rowedge[tid]] = s > 0.f ? s : 0.01f * s;
    }
  } else {     // e_out writeback (coalesced per original edge id)
    int row = tid >> 3, p = tid & 7;
    uint4 v0 = *reinterpret_cast<const uint4*>(&Eo[row * 136 + p * 16]);
    uint4 v1 = *reinterpret_cast<const uint4*>(&Eo[row * 136 + p * 16 + 8]);
    u16* dst = e_out + (size_t)rowedge[row] * 128 + p * 16;
    *reinterpret_cast<uint4*>(dst) = v0;
    *reinterpret_cast<uint4*>(dst + 8) = v1;
  }
}

// ---------------- per-node: edge GEMM + sparsemax + aggregate + MLP + fc ----------------
__global__ __launch_bounds__(256) void node_kernel(
    const float* __restrict__ nf, const u16* __restrict__ e_out,
    const float* __restrict__ aval_g,
    const float* __restrict__ eoW, const float* __restrict__ eob,
    const float* __restrict__ ndW, const float* __restrict__ ndb,
    const float* __restrict__ fcW, const float* __restrict__ fcb,
    const int* __restrict__ srci, const u16* __restrict__ eoWt,
    float* __restrict__ out)
{
  const int node = blockIdx.x;
  const int tid = threadIdx.x;
  const int ebase = node * 32;
  const int w = tid >> 6, lane = tid & 63, l15 = lane & 15, lhi = lane >> 4;

  __shared__ __align__(16) u16 A2[32 * 264];
  __shared__ __align__(16) u16 Msh[32 * 136];
  __shared__ float selfh[128], aval[32], zsrc[32], zs[32], redf[32], alpha_s[32];
  __shared__ float hagg[128], acts[128];
  __shared__ int redi[32];

  { // stage [h_src | e_out] -> A2[32][256] stride 264
    const int row = tid >> 3, p = tid & 7;
    const int src = srci[ebase + row];
    const float* ph = nf + (size_t)src * 128 + p * 16;
#pragma unroll
    for (int i = 0; i < 16; ++i) A2[row * 264 + p * 16 + i] = f2bf(ph[i]);
    const u16* pe = e_out + (size_t)(ebase + row) * 128 + p * 16;
    *reinterpret_cast<uint4*>(&A2[row * 264 + 128 + p * 16]) =
        *reinterpret_cast<const uint4*>(pe);
    *reinterpret_cast<uint4*>(&A2[row * 264 + 128 + p * 16 + 8]) =
        *reinterpret_cast<const uint4*>(pe + 8);
  }
  if (tid < 128) selfh[tid] = nf[(size_t)node * 128 + tid];
  else if (tid < 160) aval[tid - 128] = aval_g[ebase + tid - 128];
  __syncthreads();

  { // edge GEMM: M = relu([h_src | e_out] @ eoW + eob)
    f32x4 eacc[2][2];
    const int j0 = w * 32 + l15, j1 = w * 32 + 16 + l15;
    {
      float v0 = eob[j0], v1 = eob[j1];
      f32x4 t0 = {v0, v0, v0, v0}, t1 = {v1, v1, v1, v1};
      eacc[0][0] = t0; eacc[1][0] = t0;
      eacc[0][1] = t1; eacc[1][1] = t1;
    }
#pragma unroll
    for (int ks = 0; ks < 8; ++ks) {
      bf16x8 a0 = ldb8(&A2[l15 * 264 + ks * 32 + lhi * 8]);
      bf16x8 a1 = ldb8(&A2[(16 + l15) * 264 + ks * 32 + lhi * 8]);
      bf16x8 b0 = ldb8(eoWt + (size_t)j0 * 256 + ks * 32 + lhi * 8);
      bf16x8 b1 = ldb8(eoWt + (size_t)j1 * 256 + ks * 32 + lhi * 8);
      eacc[0][0] = mfma16(a0, b0, eacc[0][0]);
      eacc[1][0] = mfma16(a1, b0, eacc[1][0]);
      eacc[0][1] = mfma16(a0, b1, eacc[0][1]);
      eacc[1][1] = mfma16(a1, b1, eacc[1][1]);
    }
#pragma unroll
    for (int m = 0; m < 2; ++m)
#pragma unroll
      for (int n = 0; n < 2; ++n)
#pragma unroll
        for (int r = 0; r < 4; ++r) {
          const int row = m * 16 + lhi * 4 + r;
          const int j = w * 32 + n * 16 + l15;
          Msh[row * 136 + j] = f2bf(fmaxf(eacc[m][n][r], 0.f));
        }
  }
  __syncthreads();

  // sparsemax over aval[32]
  if (tid < 32) {
    float mx = -1e30f;
    for (int jj = 0; jj < 32; ++jj) mx = fmaxf(mx, aval[jj]);
    float z = aval[tid] - mx;
    zsrc[tid] = z;
    int rank = 0;
    for (int jj = 0; jj < 32; ++jj) {
      float zj = aval[jj] - mx;
      rank += (zj > z) || (zj == z && jj < tid);
    }
    zs[rank] = z;
  }
  __syncthreads();
  if (tid < 32) {
    float cum = 0.f;
    for (int s = 0; s <= tid; ++s) cum += zs[s];
    float zst = zs[tid];
    bool isg = (1.f + (float)(tid + 1) * zst) > cum;
    redf[tid] = isg ? zst : 0.f;
    redi[tid] = isg ? (tid + 1) : 0;
  }
  __syncthreads();
  if (tid < 32) {
    int kk = 0; float ss = 0.f;
    for (int jj = 0; jj < 32; ++jj) { kk = max(kk, redi[jj]); ss += redf[jj]; }
    float tau = (ss - 1.f) / (float)kk;
    alpha_s[tid] = fmaxf(0.f, zsrc[tid] - tau);
  }
  __syncthreads();

  // h_agg = sum_d alpha_d * M[d] - self_h_tmp
  if (tid < 128) {
    float s = 0.f;
    for (int d = 0; d < 32; ++d) s += alpha_s[d] * bf2f(Msh[d * 136 + tid]);
    float st = eob[tid];
    for (int k2 = 0; k2 < 128; ++k2) st += selfh[k2] * eoW[k2 * 128 + tid];
    hagg[tid] = s - st;
  }
  __syncthreads();
  if (tid < 128) {
    float Av = ndb[tid];
    for (int k2 = 0; k2 < 128; ++k2) Av += selfh[k2] * ndW[k2 * 128 + tid];
    for (int k2 = 0; k2 < 128; ++k2) Av += hagg[k2] * ndW[(128 + k2) * 128 + tid];
    acts[tid] = fmaxf(Av, 0.f);
  }
  __syncthreads();
  if (tid < 10) {
    float o = fcb[tid];
    for (int k = 0; k < 128; ++k) o += acts[k] * fcW[k * 10 + tid];
    out[node * 10 + tid] = o;   // FLOAT32 output
  }
}

extern "C" void kernel_launch(void* const* d_in, const int* in_sizes, int n_in,
                              void* d_out, int out_size, void* d_ws, size_t ws_size,
                              hipStream_t stream)
{
  const float* nf   = (const float*)d_in[0];
  const float* e    = (const float*)d_in[1];
  const float* dtt  = (const float*)d_in[2];
  const float* W_m  = (const float*)d_in[3];
  const float* U_m  = (const float*)d_in[4];
  const float* b_m  = (const float*)d_in[5];
  const float* Wd_m = (const float*)d_in[6];
  const float* bd_m = (const float*)d_in[7];
  const float* W_a  = (const float*)d_in[8];
  const float* U_a  = (const float*)d_in[9];
  const float* b_a  = (const float*)d_in[10];
  const float* Wd_a = (const float*)d_in[11];
  const float* bd_a = (const float*)d_in[12];
  const float* attn = (const float*)d_in[13];
  const float* eoW  = (const float*)d_in[14];
  const float* eob  = (const float*)d_in[15];
  const float* ndW  = (const float*)d_in[16];
  const float* ndb  = (const float*)d_in[17];
  const float* fcW  = (const float*)d_in[18];
  const float* fcb  = (const float*)d_in[19];
  const int* elen = (const int*)d_in[20];
  const int* srci = (const int*)d_in[21];

  char* ws = (char*)d_ws;
  u16* UWt_m  = (u16*)(ws + 0);
  u16* UWt_a  = (u16*)(ws + 163840);
  u16* WdT_m  = (u16*)(ws + 327680);
  u16* WdT_a  = (u16*)(ws + 360448);
  u16* eoWt   = (u16*)(ws + 393216);          // ends 458752
  u16* e_out  = (u16*)(ws + 458752);          // 16,777,216 B
  float* aval = (float*)(ws + 17235968);      // 262,144 B
  int* perm   = (int*)(ws + 17498112);        // 262,144 B
  int* cnt    = (int*)(ws + 17760256);        // 64 B
  int* coff   = (int*)(ws + 17760320);        // 64 B   (total ~17.76 MB)

  hipMemsetAsync(cnt, 0, 64, stream);
  prep_kernel<<<896, 256, 0, stream>>>(U_m, W_m, U_a, W_a, Wd_m, Wd_a, eoW,
                                       UWt_m, UWt_a, WdT_m, WdT_a, eoWt);
  hist_kernel<<<EDGES / 256, 256, 0, stream>>>(elen, cnt);
  scan_kernel<<<1, 1, 0, stream>>>(cnt, coff);
  scatter_kernel<<<EDGES / 256, 256, 0, stream>>>(elen, coff, perm);
  lstm_kernel<<<4096, 256, 0, stream>>>(e, dtt, b_m, bd_m, b_a, bd_a, attn,
                                        elen, perm, UWt_m, UWt_a, WdT_m, WdT_a,
                                        e_out, aval);
  node_kernel<<<NDST, 256, 0, stream>>>(nf, e_out, aval, eoW, eob, ndW, ndb,
                                        fcW, fcb, srci, eoWt, (float*)d_out);
}

// Round 8
// 1038.527 us; speedup vs baseline: 6.2153x; 1.0126x over previous
//
#include <hip/hip_runtime.h>

// GTEA T-LSTM forward. Inputs f32, OUTPUT f32. MFMA bf16 compute.
// Pipeline:
//   prep:   f32 weights -> packed bf16 UWt[512][160], WdT[128][128], eoWt[128][256]
//   sort:   counting-sort edge ids by e_len -> perm (nondeterministic permutation,
//           but outputs are bitwise independent of row grouping)
//   lstm:   4096 blocks x 256 @ 1 wave/SIMD: weights persist in VGPRs (loaded once
//           per block, reused ~8.5 steps); h/c bf16 in LDS; exact c in f32 regs.
//   node:   per dst node: edge GEMM (MFMA) + sparsemax + aggregate + MLP + fc.
// ws: 459KB weights + 16MB e_out + 256KB aval + 256KB perm + 128B counters ~= 17.8MB

typedef unsigned short u16;
typedef unsigned int u32;
typedef float f32x4 __attribute__((ext_vector_type(4)));
typedef short bf16x8 __attribute__((ext_vector_type(8)));

#define NDST 2048
#define EDGES 65536

__device__ __forceinline__ float bf2f(u16 u) {
  union { u32 i; float f; } v; v.i = ((u32)u) << 16; return v.f;
}
__device__ __forceinline__ u16 f2bf(float f) {
  u32 x = __builtin_bit_cast(u32, f);
  u32 r = x + 0x7fffu + ((x >> 16) & 1u);
  return (u16)(r >> 16);
}
// 1-op packed f32->bf16 (RNE), T12 primitive
__device__ __forceinline__ u32 cvtpk2(float lo, float hi) {
  u32 r;
  asm("v_cvt_pk_bf16_f32 %0, %1, %2" : "=v"(r) : "v"(lo), "v"(hi));
  return r;
}
__device__ __forceinline__ u16 f2bf_h(float f) { return (u16)(cvtpk2(f, f) & 0xffffu); }
__device__ __forceinline__ bf16x8 ldb8(const u16* p) {
  return *reinterpret_cast<const bf16x8*>(p);
}
__device__ __forceinline__ f32x4 mfma16(bf16x8 a, bf16x8 b, f32x4 c) {
  return __builtin_amdgcn_mfma_f32_16x16x32_bf16(a, b, c, 0, 0, 0);
}
__device__ __forceinline__ float rcp_(float x) { return __builtin_amdgcn_rcpf(x); }
__device__ __forceinline__ float sigm(float x) { return rcp_(1.f + __expf(-x)); }
__device__ __forceinline__ float tanh_(float x) { return 2.f * rcp_(1.f + __expf(-2.f * x)) - 1.f; }

// ---------------- weight prep: f32 -> packed bf16 ----------------
__global__ __launch_bounds__(256) void prep_kernel(
    const float* __restrict__ U_m, const float* __restrict__ W_m,
    const float* __restrict__ U_a, const float* __restrict__ W_a,
    const float* __restrict__ Wd_m, const float* __restrict__ Wd_a,
    const float* __restrict__ eoW,
    u16* __restrict__ UWt_m, u16* __restrict__ UWt_a,
    u16* __restrict__ WdT_m, u16* __restrict__ WdT_a, u16* __restrict__ eoWt)
{
  int idx = blockIdx.x * 256 + threadIdx.x;
  if (idx < 163840) {                          // UWt: [512 cols][160 k]
    int s = idx >= 81920 ? 1 : 0;
    int i = idx - s * 81920;
    int j = i / 160, k = i % 160;
    const float* U = s ? U_a : U_m;
    const float* W = s ? W_a : W_m;
    float v = 0.f;
    if (k < 128) v = U[k * 512 + j];
    else if (k < 144) v = W[(k - 128) * 512 + j];
    (s ? UWt_a : UWt_m)[j * 160 + k] = f2bf(v);
  } else if (idx < 196608) {                   // WdT: [128 cols][128 k]
    int i = idx - 163840;
    int s = i >= 16384 ? 1 : 0;
    i -= s * 16384;
    int j = i >> 7, k = i & 127;
    (s ? WdT_a : WdT_m)[j * 128 + k] = f2bf((s ? Wd_a : Wd_m)[k * 128 + j]);
  } else if (idx < 229376) {                   // eoWt: [128 cols][256 k]
    int i = idx - 196608;
    int j = i >> 8, k = i & 255;
    eoWt[j * 256 + k] = f2bf(eoW[k * 128 + j]);
  }
}

// ---------------- counting sort by e_len ----------------
__global__ void hist_kernel(const int* __restrict__ elen, int* __restrict__ cnt) {
  int e = blockIdx.x * 256 + threadIdx.x;
  int b = min(max(elen[e] - 1, 0), 15);
  atomicAdd(&cnt[b], 1);
}
__global__ void scan_kernel(const int* __restrict__ cnt, int* __restrict__ coff) {
  if (threadIdx.x == 0 && blockIdx.x == 0) {
    int a = 0;
    for (int i = 0; i < 16; ++i) { coff[i] = a; a += cnt[i]; }
  }
}
__global__ void scatter_kernel(const int* __restrict__ elen, int* __restrict__ coff,
                               int* __restrict__ perm) {
  int e = blockIdx.x * 256 + threadIdx.x;
  int b = min(max(elen[e] - 1, 0), 15);
  int pos = atomicAdd(&coff[b], 1);
  perm[pos] = e;
}

// ---------------- T-LSTM over 32 sorted edges; weights persistent in VGPRs ----------------
// A: stride 168 u16; cols 0..127 h(bf16), 128..143 e_t, 144..159 zero.
// C: stride 136 u16; c as bf16 (operand of c@Wd). Exact c in f32 regs.
__global__ __launch_bounds__(256, 1) void lstm_kernel(
    const float* __restrict__ e, const float* __restrict__ dtt,
    const float* __restrict__ b_m, const float* __restrict__ bd_m,
    const float* __restrict__ b_a, const float* __restrict__ bd_a,
    const float* __restrict__ attn,
    const int* __restrict__ elen, const int* __restrict__ perm,
    const u16* __restrict__ UWt_m, const u16* __restrict__ UWt_a,
    const u16* __restrict__ WdT_m, const u16* __restrict__ WdT_a,
    u16* __restrict__ e_out, float* __restrict__ aval_g)
{
  const int bid = blockIdx.x;
  const int sel = bid >> 11;             // 0 = message LSTM, 1 = attention LSTM
  const int edge0 = (bid & 2047) * 32;
  const u16* UWt = sel ? UWt_a : UWt_m;
  const u16* WdT = sel ? WdT_a : WdT_m;
  const float* bg  = sel ? b_a  : b_m;
  const float* bdp = sel ? bd_a : bd_m;

  __shared__ __align__(16) u16 A[32 * 168];
  __shared__ __align__(16) u16 C[32 * 136];
  __shared__ __align__(16) u16 Eo[32 * 136];
  __shared__ float dec_s[32];
  __shared__ int rowedge[32], elen_s[32], tmax_s;

  const int tid = threadIdx.x;
  const int w = tid >> 6, lane = tid & 63, l15 = lane & 15, lhi = lane >> 4;

  if (tid < 32) {
    int ed = perm[edge0 + tid];
    rowedge[tid] = ed;
    elen_s[tid] = min(max(elen[ed], 1), 16);
  }
  for (int i = tid; i < 32 * 168; i += 256) A[i] = 0;
  for (int i = tid; i < 32 * 136; i += 256) C[i] = 0;
  __syncthreads();
  if (tid == 0) {
    int mx = 1;
    for (int i = 0; i < 32; ++i) mx = max(mx, elen_s[i]);
    tmax_s = mx;
  }
  { // stage e_t for t=0
    int row = tid >> 3, p = tid & 7;
    float2 e2 = *reinterpret_cast<const float2*>(e + (size_t)rowedge[row] * 256 + p * 2);
    *reinterpret_cast<u32*>(&A[row * 168 + 128 + p * 2]) = cvtpk2(e2.x, e2.y);
  }

  // ---- persistent weight fragments: loaded ONCE, live across all steps ----
  bf16x8 BU[5][8];
#pragma unroll
  for (int ks = 0; ks < 5; ++ks)
#pragma unroll
    for (int n = 0; n < 8; ++n)
      BU[ks][n] = ldb8(UWt + (size_t)((n >> 1) * 128 + w * 32 + (n & 1) * 16 + l15) * 160
                       + ks * 32 + lhi * 8);
  bf16x8 BD[4][2];
#pragma unroll
  for (int ks = 0; ks < 4; ++ks)
#pragma unroll
    for (int n = 0; n < 2; ++n)
      BD[ks][n] = ldb8(WdT + (size_t)(w * 32 + n * 16 + l15) * 128 + ks * 32 + lhi * 8);

  float bgr[8];
#pragma unroll
  for (int n = 0; n < 8; ++n)
    bgr[n] = bg[(n >> 1) * 128 + w * 32 + (n & 1) * 16 + l15];
  float bdr[2];
#pragma unroll
  for (int n = 0; n < 2; ++n) bdr[n] = bdp[w * 32 + n * 16 + l15];

  float cst[2][2][4];
#pragma unroll
  for (int m = 0; m < 2; ++m)
#pragma unroll
    for (int js = 0; js < 2; ++js)
#pragma unroll
      for (int r = 0; r < 4; ++r) cst[m][js][r] = 0.f;
  __syncthreads();
  const int tmax = tmax_s;

  for (int t = 0; t < tmax; ++t) {
    if (tid < 32)
      dec_s[tid] = 1.f / logf(2.7182818284590452f + dtt[(size_t)rowedge[tid] * 16 + t]);

    f32x4 acc[2][8];
#pragma unroll
    for (int m = 0; m < 2; ++m)
#pragma unroll
      for (int n = 0; n < 8; ++n) {
        float b = bgr[n];
        f32x4 tmp = {b, b, b, b};
        acc[m][n] = tmp;
      }
    f32x4 accs[2][2];
#pragma unroll
    for (int m = 0; m < 2; ++m)
#pragma unroll
      for (int n = 0; n < 2; ++n) {
        float b = bdr[n];
        f32x4 tmp = {b, b, b, b};
        accs[m][n] = tmp;
      }
#pragma unroll
    for (int ks = 0; ks < 5; ++ks) {
      bf16x8 a0 = ldb8(&A[l15 * 168 + ks * 32 + lhi * 8]);
      bf16x8 a1 = ldb8(&A[(16 + l15) * 168 + ks * 32 + lhi * 8]);
#pragma unroll
      for (int n = 0; n < 8; ++n) {
        acc[0][n] = mfma16(a0, BU[ks][n], acc[0][n]);
        acc[1][n] = mfma16(a1, BU[ks][n], acc[1][n]);
      }
    }
#pragma unroll
    for (int ks = 0; ks < 4; ++ks) {
      bf16x8 c0 = ldb8(&C[l15 * 136 + ks * 32 + lhi * 8]);
      bf16x8 c1 = ldb8(&C[(16 + l15) * 136 + ks * 32 + lhi * 8]);
#pragma unroll
      for (int n = 0; n < 2; ++n) {
        accs[0][n] = mfma16(c0, BD[ks][n], accs[0][n]);
        accs[1][n] = mfma16(c1, BD[ks][n], accs[1][n]);
      }
    }
    __syncthreads();

#pragma unroll
    for (int m = 0; m < 2; ++m)
#pragma unroll
      for (int js = 0; js < 2; ++js)
#pragma unroll
        for (int r = 0; r < 4; ++r) {
          const int row = m * 16 + lhi * 4 + r;
          float iv = sigm(acc[m][js][r]);
          float fv = sigm(acc[m][2 + js][r]);
          float ov = sigm(acc[m][4 + js][r]);
          float gv = tanh_(acc[m][6 + js][r]);
          float cs = tanh_(accs[m][js][r]);
          float dec = dec_s[row];
          float co = cst[m][js][r];
          float cstar = co + cs * (dec - 1.f);   // c - c_s + c_s*dec
          float cn = fv * cstar + iv * gv;
          float hn = ov * tanh_(cn);
          cst[m][js][r] = cn;
          const int j = w * 32 + js * 16 + l15;
          u16 hb = f2bf_h(hn);
          A[row * 168 + j] = hb;
          C[row * 136 + j] = f2bf_h(cn);
          if (elen_s[row] == t + 1) Eo[row * 136 + j] = hb;
        }
    if (t + 1 < tmax) { // stage next e_t
      int row = tid >> 3, p = tid & 7;
      float2 e2 = *reinterpret_cast<const float2*>(
          e + (size_t)rowedge[row] * 256 + (t + 1) * 16 + p * 2);
      *reinterpret_cast<u32*>(&A[row * 168 + 128 + p * 2]) = cvtpk2(e2.x, e2.y);
    }
    __syncthreads();
  }

  if (sel) {   // attention logit: leaky_relu(h . attn_w)
    if (tid < 32) {
      float s = 0.f;
      for (int k = 0; k < 128; ++k) s += bf2f(Eo[tid * 136 + k]) * attn[k];
      aval_g[rowedge[tid]] = s > 0.f ? s : 0.01f * s;
    }
  } else {     // e_out writeback
    int row = tid >> 3, p = tid & 7;
    uint4 v0 = *reinterpret_cast<const uint4*>(&Eo[row * 136 + p * 16]);
    uint4 v1 = *reinterpret_cast<const uint4*>(&Eo[row * 136 + p * 16 + 8]);
    u16* dst = e_out + (size_t)rowedge[row] * 128 + p * 16;
    *reinterpret_cast<uint4*>(dst) = v0;
    *reinterpret_cast<uint4*>(dst + 8) = v1;
  }
}

// ---------------- per-node: edge GEMM + sparsemax + aggregate + MLP + fc ----------------
__global__ __launch_bounds__(256) void node_kernel(
    const float* __restrict__ nf, const u16* __restrict__ e_out,
    const float* __restrict__ aval_g,
    const float* __restrict__ eoW, const float* __restrict__ eob,
    const float* __restrict__ ndW, const float* __restrict__ ndb,
    const float* __restrict__ fcW, const float* __restrict__ fcb,
    const int* __restrict__ srci, const u16* __restrict__ eoWt,
    float* __restrict__ out)
{
  const int node = blockIdx.x;
  const int tid = threadIdx.x;
  const int ebase = node * 32;
  const int w = tid >> 6, lane = tid & 63, l15 = lane & 15, lhi = lane >> 4;

  __shared__ __align__(16) u16 A2[32 * 264];
  __shared__ __align__(16) u16 Msh[32 * 136];
  __shared__ float selfh[128], aval[32], zsrc[32], zs[32], redf[32], alpha_s[32];
  __shared__ float hagg[128], acts[128], part[2][128];
  __shared__ int redi[32];

  { // stage [h_src | e_out] -> A2[32][256] stride 264 (vectorized)
    const int row = tid >> 3, p = tid & 7;
    const int src = srci[ebase + row];
    const float4* ph = reinterpret_cast<const float4*>(nf + (size_t)src * 128 + p * 16);
    float4 f0 = ph[0], f1 = ph[1], f2 = ph[2], f3 = ph[3];
    uint4 pk0, pk1;
    pk0.x = cvtpk2(f0.x, f0.y); pk0.y = cvtpk2(f0.z, f0.w);
    pk0.z = cvtpk2(f1.x, f1.y); pk0.w = cvtpk2(f1.z, f1.w);
    pk1.x = cvtpk2(f2.x, f2.y); pk1.y = cvtpk2(f2.z, f2.w);
    pk1.z = cvtpk2(f3.x, f3.y); pk1.w = cvtpk2(f3.z, f3.w);
    *reinterpret_cast<uint4*>(&A2[row * 264 + p * 16]) = pk0;
    *reinterpret_cast<uint4*>(&A2[row * 264 + p * 16 + 8]) = pk1;
    const u16* pe = e_out + (size_t)(ebase + row) * 128 + p * 16;
    *reinterpret_cast<uint4*>(&A2[row * 264 + 128 + p * 16]) =
        *reinterpret_cast<const uint4*>(pe);
    *reinterpret_cast<uint4*>(&A2[row * 264 + 128 + p * 16 + 8]) =
        *reinterpret_cast<const uint4*>(pe + 8);
  }
  if (tid < 128) selfh[tid] = nf[(size_t)node * 128 + tid];
  else if (tid < 160) aval[tid - 128] = aval_g[ebase + tid - 128];
  __syncthreads();

  { // edge GEMM: M = relu([h_src | e_out] @ eoW + eob)
    f32x4 eacc[2][2];
    const int j0 = w * 32 + l15, j1 = w * 32 + 16 + l15;
    {
      float v0 = eob[j0], v1 = eob[j1];
      f32x4 t0 = {v0, v0, v0, v0}, t1 = {v1, v1, v1, v1};
      eacc[0][0] = t0; eacc[1][0] = t0;
      eacc[0][1] = t1; eacc[1][1] = t1;
    }
#pragma unroll
    for (int ks = 0; ks < 8; ++ks) {
      bf16x8 a0 = ldb8(&A2[l15 * 264 + ks * 32 + lhi * 8]);
      bf16x8 a1 = ldb8(&A2[(16 + l15) * 264 + ks * 32 + lhi * 8]);
      bf16x8 b0 = ldb8(eoWt + (size_t)j0 * 256 + ks * 32 + lhi * 8);
      bf16x8 b1 = ldb8(eoWt + (size_t)j1 * 256 + ks * 32 + lhi * 8);
      eacc[0][0] = mfma16(a0, b0, eacc[0][0]);
      eacc[1][0] = mfma16(a1, b0, eacc[1][0]);
      eacc[0][1] = mfma16(a0, b1, eacc[0][1]);
      eacc[1][1] = mfma16(a1, b1, eacc[1][1]);
    }
#pragma unroll
    for (int m = 0; m < 2; ++m)
#pragma unroll
      for (int n = 0; n < 2; ++n)
#pragma unroll
        for (int r = 0; r < 4; ++r) {
          const int row = m * 16 + lhi * 4 + r;
          const int j = w * 32 + n * 16 + l15;
          Msh[row * 136 + j] = f2bf_h(fmaxf(eacc[m][n][r], 0.f));
        }
  }
  __syncthreads();

  // sparsemax over aval[32]
  if (tid < 32) {
    float mx = -1e30f;
    for (int jj = 0; jj < 32; ++jj) mx = fmaxf(mx, aval[jj]);
    float z = aval[tid] - mx;
    zsrc[tid] = z;
    int rank = 0;
    for (int jj = 0; jj < 32; ++jj) {
      float zj = aval[jj] - mx;
      rank += (zj > z) || (zj == z && jj < tid);
    }
    zs[rank] = z;
  }
  __syncthreads();
  if (tid < 32) {
    float cum = 0.f;
    for (int s = 0; s <= tid; ++s) cum += zs[s];
    float zst = zs[tid];
    bool isg = (1.f + (float)(tid + 1) * zst) > cum;
    redf[tid] = isg ? zst : 0.f;
    redi[tid] = isg ? (tid + 1) : 0;
  }
  __syncthreads();
  if (tid < 32) {
    int kk = 0; float ss = 0.f;
    for (int jj = 0; jj < 32; ++jj) { kk = max(kk, redi[jj]); ss += redf[jj]; }
    float tau = (ss - 1.f) / (float)kk;
    alpha_s[tid] = fmaxf(0.f, zsrc[tid] - tau);
  }
  __syncthreads();

  // h_agg = sum_d alpha_d * M[d] - self_h_tmp   (split across both half-blocks)
  const int col = tid & 127, half = tid >> 7;
  if (half == 0) {
    float s = 0.f;
    for (int d = 0; d < 32; ++d) s += alpha_s[d] * bf2f(Msh[d * 136 + col]);
    part[0][col] = s;
  } else {
    float st = eob[col];
    for (int k2 = 0; k2 < 128; ++k2) st += selfh[k2] * eoW[k2 * 128 + col];
    part[1][col] = st;
  }
  __syncthreads();
  if (tid < 128) hagg[tid] = part[0][tid] - part[1][tid];
  __syncthreads();

  // node MLP: each column's 256-term dot split across 2 threads
  {
    float Av = half ? 0.f : ndb[col];
    const int k0 = half * 64;
    for (int k2 = k0; k2 < k0 + 64; ++k2) Av += selfh[k2] * ndW[k2 * 128 + col];
    for (int k2 = k0; k2 < k0 + 64; ++k2) Av += hagg[k2] * ndW[(128 + k2) * 128 + col];
    part[half][col] = Av;
  }
  __syncthreads();
  if (tid < 128) acts[tid] = fmaxf(part[0][tid] + part[1][tid], 0.f);
  __syncthreads();

  // fc: 10 classes x 4 lanes each (32 terms/lane, shfl-reduce)
  if (tid < 40) {
    const int cls = tid >> 2, q = tid & 3;
    float o = 0.f;
    for (int k = q * 32; k < q * 32 + 32; ++k) o += acts[k] * fcW[k * 10 + cls];
    o += __shfl_xor(o, 1);
    o += __shfl_xor(o, 2);
    if (q == 0) out[node * 10 + cls] = o + fcb[cls];
  }
}

extern "C" void kernel_launch(void* const* d_in, const int* in_sizes, int n_in,
                              void* d_out, int out_size, void* d_ws, size_t ws_size,
                              hipStream_t stream)
{
  const float* nf   = (const float*)d_in[0];
  const float* e    = (const float*)d_in[1];
  const float* dtt  = (const float*)d_in[2];
  const float* W_m  = (const float*)d_in[3];
  const float* U_m  = (const float*)d_in[4];
  const float* b_m  = (const float*)d_in[5];
  const float* Wd_m = (const float*)d_in[6];
  const float* bd_m = (const float*)d_in[7];
  const float* W_a  = (const float*)d_in[8];
  const float* U_a  = (const float*)d_in[9];
  const float* b_a  = (const float*)d_in[10];
  const float* Wd_a = (const float*)d_in[11];
  const float* bd_a = (const float*)d_in[12];
  const float* attn = (const float*)d_in[13];
  const float* eoW  = (const float*)d_in[14];
  const float* eob  = (const float*)d_in[15];
  const float* ndW  = (const float*)d_in[16];
  const float* ndb  = (const float*)d_in[17];
  const float* fcW  = (const float*)d_in[18];
  const float* fcb  = (const float*)d_in[19];
  const int* elen = (const int*)d_in[20];
  const int* srci = (const int*)d_in[21];

  char* ws = (char*)d_ws;
  u16* UWt_m  = (u16*)(ws + 0);
  u16* UWt_a  = (u16*)(ws + 163840);
  u16* WdT_m  = (u16*)(ws + 327680);
  u16* WdT_a  = (u16*)(ws + 360448);
  u16* eoWt   = (u16*)(ws + 393216);          // ends 458752
  u16* e_out  = (u16*)(ws + 458752);          // 16,777,216 B
  float* aval = (float*)(ws + 17235968);      // 262,144 B
  int* perm   = (int*)(ws + 17498112);        // 262,144 B
  int* cnt    = (int*)(ws + 17760256);        // 64 B
  int* coff   = (int*)(ws + 17760320);        // 64 B

  hipMemsetAsync(cnt, 0, 64, stream);
  prep_kernel<<<896, 256, 0, stream>>>(U_m, W_m, U_a, W_a, Wd_m, Wd_a, eoW,
                                       UWt_m, UWt_a, WdT_m, WdT_a, eoWt);
  hist_kernel<<<EDGES / 256, 256, 0, stream>>>(elen, cnt);
  scan_kernel<<<1, 1, 0, stream>>>(cnt, coff);
  scatter_kernel<<<EDGES / 256, 256, 0, stream>>>(elen, coff, perm);
  lstm_kernel<<<4096, 256, 0, stream>>>(e, dtt, b_m, bd_m, b_a, bd_a, attn,
                                        elen, perm, UWt_m, UWt_a, WdT_m, WdT_a,
                                        e_out, aval);
  node_kernel<<<NDST, 256, 0, stream>>>(nf, e_out, aval, eoW, eob, ndW, ndb,
                                        fcW, fcb, srci, eoWt, (float*)d_out);
}

// Round 9
// 1034.491 us; speedup vs baseline: 6.2396x; 1.0039x over previous
//
#include <hip/hip_runtime.h>

// GTEA T-LSTM forward. Inputs f32, OUTPUT f32. MFMA bf16 compute.
// Pipeline:
//   prep:   f32 weights -> packed bf16 UWt[512][160], WdT[128][128], eoWt[128][256]
//   sort:   counting-sort edge ids by e_len -> perm (nondeterministic permutation,
//           but outputs are bitwise independent of row grouping)
//   lstm:   4096 blocks x 256 @ amdgpu_waves_per_eu(1,1): 512-VGPR budget so the
//           48 weight fragments persist in VGPRs across all steps (no L2 refetch).
//   node:   per dst node: edge GEMM (MFMA) + sparsemax + aggregate + MLP + fc.
// ws: 459KB weights + 16MB e_out + 256KB aval + 256KB perm + 128B counters ~= 17.8MB

typedef unsigned short u16;
typedef unsigned int u32;
typedef float f32x4 __attribute__((ext_vector_type(4)));
typedef short bf16x8 __attribute__((ext_vector_type(8)));

#define NDST 2048
#define EDGES 65536

__device__ __forceinline__ float bf2f(u16 u) {
  union { u32 i; float f; } v; v.i = ((u32)u) << 16; return v.f;
}
__device__ __forceinline__ u16 f2bf(float f) {
  u32 x = __builtin_bit_cast(u32, f);
  u32 r = x + 0x7fffu + ((x >> 16) & 1u);
  return (u16)(r >> 16);
}
// 1-op packed f32->bf16 (RNE), T12 primitive
__device__ __forceinline__ u32 cvtpk2(float lo, float hi) {
  u32 r;
  asm("v_cvt_pk_bf16_f32 %0, %1, %2" : "=v"(r) : "v"(lo), "v"(hi));
  return r;
}
__device__ __forceinline__ u16 f2bf_h(float f) { return (u16)(cvtpk2(f, f) & 0xffffu); }
__device__ __forceinline__ bf16x8 ldb8(const u16* p) {
  return *reinterpret_cast<const bf16x8*>(p);
}
__device__ __forceinline__ f32x4 mfma16(bf16x8 a, bf16x8 b, f32x4 c) {
  return __builtin_amdgcn_mfma_f32_16x16x32_bf16(a, b, c, 0, 0, 0);
}
__device__ __forceinline__ float rcp_(float x) { return __builtin_amdgcn_rcpf(x); }
__device__ __forceinline__ float sigm(float x) { return rcp_(1.f + __expf(-x)); }
__device__ __forceinline__ float tanh_(float x) { return 2.f * rcp_(1.f + __expf(-2.f * x)) - 1.f; }

// ---------------- weight prep: f32 -> packed bf16 ----------------
__global__ __launch_bounds__(256) void prep_kernel(
    const float* __restrict__ U_m, const float* __restrict__ W_m,
    const float* __restrict__ U_a, const float* __restrict__ W_a,
    const float* __restrict__ Wd_m, const float* __restrict__ Wd_a,
    const float* __restrict__ eoW,
    u16* __restrict__ UWt_m, u16* __restrict__ UWt_a,
    u16* __restrict__ WdT_m, u16* __restrict__ WdT_a, u16* __restrict__ eoWt)
{
  int idx = blockIdx.x * 256 + threadIdx.x;
  if (idx < 163840) {                          // UWt: [512 cols][160 k]
    int s = idx >= 81920 ? 1 : 0;
    int i = idx - s * 81920;
    int j = i / 160, k = i % 160;
    const float* U = s ? U_a : U_m;
    const float* W = s ? W_a : W_m;
    float v = 0.f;
    if (k < 128) v = U[k * 512 + j];
    else if (k < 144) v = W[(k - 128) * 512 + j];
    (s ? UWt_a : UWt_m)[j * 160 + k] = f2bf(v);
  } else if (idx < 196608) {                   // WdT: [128 cols][128 k]
    int i = idx - 163840;
    int s = i >= 16384 ? 1 : 0;
    i -= s * 16384;
    int j = i >> 7, k = i & 127;
    (s ? WdT_a : WdT_m)[j * 128 + k] = f2bf((s ? Wd_a : Wd_m)[k * 128 + j]);
  } else if (idx < 229376) {                   // eoWt: [128 cols][256 k]
    int i = idx - 196608;
    int j = i >> 8, k = i & 255;
    eoWt[j * 256 + k] = f2bf(eoW[k * 128 + j]);
  }
}

// ---------------- counting sort by e_len ----------------
__global__ void hist_kernel(const int* __restrict__ elen, int* __restrict__ cnt) {
  int e = blockIdx.x * 256 + threadIdx.x;
  int b = min(max(elen[e] - 1, 0), 15);
  atomicAdd(&cnt[b], 1);
}
__global__ void scan_kernel(const int* __restrict__ cnt, int* __restrict__ coff) {
  if (threadIdx.x == 0 && blockIdx.x == 0) {
    int a = 0;
    for (int i = 0; i < 16; ++i) { coff[i] = a; a += cnt[i]; }
  }
}
__global__ void scatter_kernel(const int* __restrict__ elen, int* __restrict__ coff,
                               int* __restrict__ perm) {
  int e = blockIdx.x * 256 + threadIdx.x;
  int b = min(max(elen[e] - 1, 0), 15);
  int pos = atomicAdd(&coff[b], 1);
  perm[pos] = e;
}

// ---------------- T-LSTM over 32 sorted edges; weights persistent in VGPRs ----------------
// A: stride 168 u16; cols 0..127 h(bf16), 128..143 e_t, 144..159 zero.
// C: stride 136 u16; c as bf16 (operand of c@Wd). Exact c in f32 regs.
// amdgpu_waves_per_eu(1,1): pin 1 wave/SIMD -> 512-VGPR budget -> the 48
// weight fragments stay resident instead of being re-fetched from L2 each step.
__global__ __attribute__((amdgpu_waves_per_eu(1, 1))) __launch_bounds__(256)
void lstm_kernel(
    const float* __restrict__ e, const float* __restrict__ dtt,
    const float* __restrict__ b_m, const float* __restrict__ bd_m,
    const float* __restrict__ b_a, const float* __restrict__ bd_a,
    const float* __restrict__ attn,
    const int* __restrict__ elen, const int* __restrict__ perm,
    const u16* __restrict__ UWt_m, const u16* __restrict__ UWt_a,
    const u16* __restrict__ WdT_m, const u16* __restrict__ WdT_a,
    u16* __restrict__ e_out, float* __restrict__ aval_g)
{
  const int bid = blockIdx.x;
  const int sel = bid >> 11;             // 0 = message LSTM, 1 = attention LSTM
  const int edge0 = (bid & 2047) * 32;
  const u16* UWt = sel ? UWt_a : UWt_m;
  const u16* WdT = sel ? WdT_a : WdT_m;
  const float* bg  = sel ? b_a  : b_m;
  const float* bdp = sel ? bd_a : bd_m;

  __shared__ __align__(16) u16 A[32 * 168];
  __shared__ __align__(16) u16 C[32 * 136];
  __shared__ __align__(16) u16 Eo[32 * 136];
  __shared__ float dec_s[32];
  __shared__ int rowedge[32], elen_s[32], tmax_s;

  const int tid = threadIdx.x;
  const int w = tid >> 6, lane = tid & 63, l15 = lane & 15, lhi = lane >> 4;

  if (tid < 32) {
    int ed = perm[edge0 + tid];
    rowedge[tid] = ed;
    elen_s[tid] = min(max(elen[ed], 1), 16);
  }
  for (int i = tid; i < 32 * 168; i += 256) A[i] = 0;
  for (int i = tid; i < 32 * 136; i += 256) C[i] = 0;
  __syncthreads();
  if (tid == 0) {
    int mx = 1;
    for (int i = 0; i < 32; ++i) mx = max(mx, elen_s[i]);
    tmax_s = mx;
  }
  { // stage e_t for t=0
    int row = tid >> 3, p = tid & 7;
    float2 e2 = *reinterpret_cast<const float2*>(e + (size_t)rowedge[row] * 256 + p * 2);
    *reinterpret_cast<u32*>(&A[row * 168 + 128 + p * 2]) = cvtpk2(e2.x, e2.y);
  }

  // ---- persistent weight fragments: loaded ONCE, live across all steps ----
  bf16x8 BU[5][8];
#pragma unroll
  for (int ks = 0; ks < 5; ++ks)
#pragma unroll
    for (int n = 0; n < 8; ++n)
      BU[ks][n] = ldb8(UWt + (size_t)((n >> 1) * 128 + w * 32 + (n & 1) * 16 + l15) * 160
                       + ks * 32 + lhi * 8);
  bf16x8 BD[4][2];
#pragma unroll
  for (int ks = 0; ks < 4; ++ks)
#pragma unroll
    for (int n = 0; n < 2; ++n)
      BD[ks][n] = ldb8(WdT + (size_t)(w * 32 + n * 16 + l15) * 128 + ks * 32 + lhi * 8);

  float bgr[8];
#pragma unroll
  for (int n = 0; n < 8; ++n)
    bgr[n] = bg[(n >> 1) * 128 + w * 32 + (n & 1) * 16 + l15];
  float bdr[2];
#pragma unroll
  for (int n = 0; n < 2; ++n) bdr[n] = bdp[w * 32 + n * 16 + l15];

  float cst[2][2][4];
#pragma unroll
  for (int m = 0; m < 2; ++m)
#pragma unroll
    for (int js = 0; js < 2; ++js)
#pragma unroll
      for (int r = 0; r < 4; ++r) cst[m][js][r] = 0.f;
  __syncthreads();
  const int tmax = tmax_s;

  for (int t = 0; t < tmax; ++t) {
    if (tid < 32)
      dec_s[tid] = 1.f / logf(2.7182818284590452f + dtt[(size_t)rowedge[tid] * 16 + t]);

    f32x4 acc[2][8];
#pragma unroll
    for (int m = 0; m < 2; ++m)
#pragma unroll
      for (int n = 0; n < 8; ++n) {
        float b = bgr[n];
        f32x4 tmp = {b, b, b, b};
        acc[m][n] = tmp;
      }
    f32x4 accs[2][2];
#pragma unroll
    for (int m = 0; m < 2; ++m)
#pragma unroll
      for (int n = 0; n < 2; ++n) {
        float b = bdr[n];
        f32x4 tmp = {b, b, b, b};
        accs[m][n] = tmp;
      }
#pragma unroll
    for (int ks = 0; ks < 5; ++ks) {
      bf16x8 a0 = ldb8(&A[l15 * 168 + ks * 32 + lhi * 8]);
      bf16x8 a1 = ldb8(&A[(16 + l15) * 168 + ks * 32 + lhi * 8]);
#pragma unroll
      for (int n = 0; n < 8; ++n) {
        acc[0][n] = mfma16(a0, BU[ks][n], acc[0][n]);
        acc[1][n] = mfma16(a1, BU[ks][n], acc[1][n]);
      }
    }
#pragma unroll
    for (int ks = 0; ks < 4; ++ks) {
      bf16x8 c0 = ldb8(&C[l15 * 136 + ks * 32 + lhi * 8]);
      bf16x8 c1 = ldb8(&C[(16 + l15) * 136 + ks * 32 + lhi * 8]);
#pragma unroll
      for (int n = 0; n < 2; ++n) {
        accs[0][n] = mfma16(c0, BD[ks][n], accs[0][n]);
        accs[1][n] = mfma16(c1, BD[ks][n], accs[1][n]);
      }
    }
    __syncthreads();

#pragma unroll
    for (int m = 0; m < 2; ++m)
#pragma unroll
      for (int js = 0; js < 2; ++js)
#pragma unroll
        for (int r = 0; r < 4; ++r) {
          const int row = m * 16 + lhi * 4 + r;
          float iv = sigm(acc[m][js][r]);
          float fv = sigm(acc[m][2 + js][r]);
          float ov = sigm(acc[m][4 + js][r]);
          float gv = tanh_(acc[m][6 + js][r]);
          float cs = tanh_(accs[m][js][r]);
          float dec = dec_s[row];
          float co = cst[m][js][r];
          float cstar = co + cs * (dec - 1.f);   // c - c_s + c_s*dec
          float cn = fv * cstar + iv * gv;
          float hn = ov * tanh_(cn);
          cst[m][js][r] = cn;
          const int j = w * 32 + js * 16 + l15;
          u16 hb = f2bf_h(hn);
          A[row * 168 + j] = hb;
          C[row * 136 + j] = f2bf_h(cn);
          if (elen_s[row] == t + 1) Eo[row * 136 + j] = hb;
        }
    if (t + 1 < tmax) { // stage next e_t
      int row = tid >> 3, p = tid & 7;
      float2 e2 = *reinterpret_cast<const float2*>(
          e + (size_t)rowedge[row] * 256 + (t + 1) * 16 + p * 2);
      *reinterpret_cast<u32*>(&A[row * 168 + 128 + p * 2]) = cvtpk2(e2.x, e2.y);
    }
    __syncthreads();
  }

  if (sel) {   // attention logit: leaky_relu(h . attn_w)
    if (tid < 32) {
      float s = 0.f;
      for (int k = 0; k < 128; ++k) s += bf2f(Eo[tid * 136 + k]) * attn[k];
      aval_g[rowedge[tid]] = s > 0.f ? s : 0.01f * s;
    }
  } else {     // e_out writeback
    int row = tid >> 3, p = tid & 7;
    uint4 v0 = *reinterpret_cast<const uint4*>(&Eo[row * 136 + p * 16]);
    uint4 v1 = *reinterpret_cast<const uint4*>(&Eo[row * 136 + p * 16 + 8]);
    u16* dst = e_out + (size_t)rowedge[row] * 128 + p * 16;
    *reinterpret_cast<uint4*>(dst) = v0;
    *reinterpret_cast<uint4*>(dst + 8) = v1;
  }
}

// ---------------- per-node: edge GEMM + sparsemax + aggregate + MLP + fc ----------------
__global__ __launch_bounds__(256) void node_kernel(
    const float* __restrict__ nf, const u16* __restrict__ e_out,
    const float* __restrict__ aval_g,
    const float* __restrict__ eoW, const float* __restrict__ eob,
    const float* __restrict__ ndW, const float* __restrict__ ndb,
    const float* __restrict__ fcW, const float* __restrict__ fcb,
    const int* __restrict__ srci, const u16* __restrict__ eoWt,
    float* __restrict__ out)
{
  const int node = blockIdx.x;
  const int tid = threadIdx.x;
  const int ebase = node * 32;
  const int w = tid >> 6, lane = tid & 63, l15 = lane & 15, lhi = lane >> 4;

  __shared__ __align__(16) u16 A2[32 * 264];
  __shared__ __align__(16) u16 Msh[32 * 136];
  __shared__ float selfh[128], aval[32], zsrc[32], zs[32], redf[32], alpha_s[32];
  __shared__ float hagg[128], acts[128], part[2][128];
  __shared__ int redi[32];

  { // stage [h_src | e_out] -> A2[32][256] stride 264 (vectorized)
    const int row = tid >> 3, p = tid & 7;
    const int src = srci[ebase + row];
    const float4* ph = reinterpret_cast<const float4*>(nf + (size_t)src * 128 + p * 16);
    float4 f0 = ph[0], f1 = ph[1], f2 = ph[2], f3 = ph[3];
    uint4 pk0, pk1;
    pk0.x = cvtpk2(f0.x, f0.y); pk0.y = cvtpk2(f0.z, f0.w);
    pk0.z = cvtpk2(f1.x, f1.y); pk0.w = cvtpk2(f1.z, f1.w);
    pk1.x = cvtpk2(f2.x, f2.y); pk1.y = cvtpk2(f2.z, f2.w);
    pk1.z = cvtpk2(f3.x, f3.y); pk1.w = cvtpk2(f3.z, f3.w);
    *reinterpret_cast<uint4*>(&A2[row * 264 + p * 16]) = pk0;
    *reinterpret_cast<uint4*>(&A2[row * 264 + p * 16 + 8]) = pk1;
    const u16* pe = e_out + (size_t)(ebase + row) * 128 + p * 16;
    *reinterpret_cast<uint4*>(&A2[row * 264 + 128 + p * 16]) =
        *reinterpret_cast<const uint4*>(pe);
    *reinterpret_cast<uint4*>(&A2[row * 264 + 128 + p * 16 + 8]) =
        *reinterpret_cast<const uint4*>(pe + 8);
  }
  if (tid < 128) selfh[tid] = nf[(size_t)node * 128 + tid];
  else if (tid < 160) aval[tid - 128] = aval_g[ebase + tid - 128];
  __syncthreads();

  { // edge GEMM: M = relu([h_src | e_out] @ eoW + eob)
    f32x4 eacc[2][2];
    const int j0 = w * 32 + l15, j1 = w * 32 + 16 + l15;
    {
      float v0 = eob[j0], v1 = eob[j1];
      f32x4 t0 = {v0, v0, v0, v0}, t1 = {v1, v1, v1, v1};
      eacc[0][0] = t0; eacc[1][0] = t0;
      eacc[0][1] = t1; eacc[1][1] = t1;
    }
#pragma unroll
    for (int ks = 0; ks < 8; ++ks) {
      bf16x8 a0 = ldb8(&A2[l15 * 264 + ks * 32 + lhi * 8]);
      bf16x8 a1 = ldb8(&A2[(16 + l15) * 264 + ks * 32 + lhi * 8]);
      bf16x8 b0 = ldb8(eoWt + (size_t)j0 * 256 + ks * 32 + lhi * 8);
      bf16x8 b1 = ldb8(eoWt + (size_t)j1 * 256 + ks * 32 + lhi * 8);
      eacc[0][0] = mfma16(a0, b0, eacc[0][0]);
      eacc[1][0] = mfma16(a1, b0, eacc[1][0]);
      eacc[0][1] = mfma16(a0, b1, eacc[0][1]);
      eacc[1][1] = mfma16(a1, b1, eacc[1][1]);
    }
#pragma unroll
    for (int m = 0; m < 2; ++m)
#pragma unroll
      for (int n = 0; n < 2; ++n)
#pragma unroll
        for (int r = 0; r < 4; ++r) {
          const int row = m * 16 + lhi * 4 + r;
          const int j = w * 32 + n * 16 + l15;
          Msh[row * 136 + j] = f2bf_h(fmaxf(eacc[m][n][r], 0.f));
        }
  }
  __syncthreads();

  // sparsemax over aval[32]
  if (tid < 32) {
    float mx = -1e30f;
    for (int jj = 0; jj < 32; ++jj) mx = fmaxf(mx, aval[jj]);
    float z = aval[tid] - mx;
    zsrc[tid] = z;
    int rank = 0;
    for (int jj = 0; jj < 32; ++jj) {
      float zj = aval[jj] - mx;
      rank += (zj > z) || (zj == z && jj < tid);
    }
    zs[rank] = z;
  }
  __syncthreads();
  if (tid < 32) {
    float cum = 0.f;
    for (int s = 0; s <= tid; ++s) cum += zs[s];
    float zst = zs[tid];
    bool isg = (1.f + (float)(tid + 1) * zst) > cum;
    redf[tid] = isg ? zst : 0.f;
    redi[tid] = isg ? (tid + 1) : 0;
  }
  __syncthreads();
  if (tid < 32) {
    int kk = 0; float ss = 0.f;
    for (int jj = 0; jj < 32; ++jj) { kk = max(kk, redi[jj]); ss += redf[jj]; }
    float tau = (ss - 1.f) / (float)kk;
    alpha_s[tid] = fmaxf(0.f, zsrc[tid] - tau);
  }
  __syncthreads();

  // h_agg = sum_d alpha_d * M[d] - self_h_tmp   (split across both half-blocks)
  const int col = tid & 127, half = tid >> 7;
  if (half == 0) {
    float s = 0.f;
    for (int d = 0; d < 32; ++d) s += alpha_s[d] * bf2f(Msh[d * 136 + col]);
    part[0][col] = s;
  } else {
    float st = eob[col];
    for (int k2 = 0; k2 < 128; ++k2) st += selfh[k2] * eoW[k2 * 128 + col];
    part[1][col] = st;
  }
  __syncthreads();
  if (tid < 128) hagg[tid] = part[0][tid] - part[1][tid];
  __syncthreads();

  // node MLP: each column's 256-term dot split across 2 threads
  {
    float Av = half ? 0.f : ndb[col];
    const int k0 = half * 64;
    for (int k2 = k0; k2 < k0 + 64; ++k2) Av += selfh[k2] * ndW[k2 * 128 + col];
    for (int k2 = k0; k2 < k0 + 64; ++k2) Av += hagg[k2] * ndW[(128 + k2) * 128 + col];
    part[half][col] = Av;
  }
  __syncthreads();
  if (tid < 128) acts[tid] = fmaxf(part[0][tid] + part[1][tid], 0.f);
  __syncthreads();

  // fc: 10 classes x 4 lanes each (32 terms/lane, shfl-reduce)
  if (tid < 40) {
    const int cls = tid >> 2, q = tid & 3;
    float o = 0.f;
    for (int k = q * 32; k < q * 32 + 32; ++k) o += acts[k] * fcW[k * 10 + cls];
    o += __shfl_xor(o, 1);
    o += __shfl_xor(o, 2);
    if (q == 0) out[node * 10 + cls] = o + fcb[cls];
  }
}

extern "C" void kernel_launch(void* const* d_in, const int* in_sizes, int n_in,
                              void* d_out, int out_size, void* d_ws, size_t ws_size,
                              hipStream_t stream)
{
  const float* nf   = (const float*)d_in[0];
  const float* e    = (const float*)d_in[1];
  const float* dtt  = (const float*)d_in[2];
  const float* W_m  = (const float*)d_in[3];
  const float* U_m  = (const float*)d_in[4];
  const float* b_m  = (const float*)d_in[5];
  const float* Wd_m = (const float*)d_in[6];
  const float* bd_m = (const float*)d_in[7];
  const float* W_a  = (const float*)d_in[8];
  const float* U_a  = (const float*)d_in[9];
  const float* b_a  = (const float*)d_in[10];
  const float* Wd_a = (const float*)d_in[11];
  const float* bd_a = (const float*)d_in[12];
  const float* attn = (const float*)d_in[13];
  const float* eoW  = (const float*)d_in[14];
  const float* eob  = (const float*)d_in[15];
  const float* ndW  = (const float*)d_in[16];
  const float* ndb  = (const float*)d_in[17];
  const float* fcW  = (const float*)d_in[18];
  const float* fcb  = (const float*)d_in[19];
  const int* elen = (const int*)d_in[20];
  const int* srci = (const int*)d_in[21];

  char* ws = (char*)d_ws;
  u16* UWt_m  = (u16*)(ws + 0);
  u16* UWt_a  = (u16*)(ws + 163840);
  u16* WdT_m  = (u16*)(ws + 327680);
  u16* WdT_a  = (u16*)(ws + 360448);
  u16* eoWt   = (u16*)(ws + 393216);          // ends 458752
  u16* e_out  = (u16*)(ws + 458752);          // 16,777,216 B
  float* aval = (float*)(ws + 17235968);      // 262,144 B
  int* perm   = (int*)(ws + 17498112);        // 262,144 B
  int* cnt    = (int*)(ws + 17760256);        // 64 B
  int* coff   = (int*)(ws + 17760320);        // 64 B

  hipMemsetAsync(cnt, 0, 64, stream);
  prep_kernel<<<896, 256, 0, stream>>>(U_m, W_m, U_a, W_a, Wd_m, Wd_a, eoW,
                                       UWt_m, UWt_a, WdT_m, WdT_a, eoWt);
  hist_kernel<<<EDGES / 256, 256, 0, stream>>>(elen, cnt);
  scan_kernel<<<1, 1, 0, stream>>>(cnt, coff);
  scatter_kernel<<<EDGES / 256, 256, 0, stream>>>(elen, coff, perm);
  lstm_kernel<<<4096, 256, 0, stream>>>(e, dtt, b_m, bd_m, b_a, bd_a, attn,
                                        elen, perm, UWt_m, UWt_a, WdT_m, WdT_a,
                                        e_out, aval);
  node_kernel<<<NDST, 256, 0, stream>>>(nf, e_out, aval, eoW, eob, ndW, ndb,
                                        fcW, fcb, srci, eoWt, (float*)d_out);
}

// Round 10
// 982.239 us; speedup vs baseline: 6.5715x; 1.0532x over previous
//
#include <hip/hip_runtime.h>

// GTEA T-LSTM forward. Inputs f32, OUTPUT f32. MFMA bf16 compute.
// Pipeline:
//   prep:   f32 weights -> packed bf16 UWt[512][160], WdT[128][128], eoWt[128][256]
//   sort:   counting-sort edge ids by e_len -> perm (nondeterministic permutation,
//           but outputs are bitwise independent of row grouping)
//   lstm:   4096 blocks x 256 @ 1 block/CU: 48 weight fragments loaded once and
//           PINNED in VGPRs via opaque asm (defeats load-sinking remat); dec
//           precomputed for all 16 steps; next-e_t staged split (load early/write late).
//   node:   per dst node: edge GEMM (MFMA) + sparsemax + aggregate + MLP + fc.
// ws: 459KB weights + 16MB e_out + 256KB aval + 256KB perm + 128B counters ~= 17.8MB

typedef unsigned short u16;
typedef unsigned int u32;
typedef float f32x4 __attribute__((ext_vector_type(4)));
typedef short bf16x8 __attribute__((ext_vector_type(8)));

#define NDST 2048
#define EDGES 65536

__device__ __forceinline__ float bf2f(u16 u) {
  union { u32 i; float f; } v; v.i = ((u32)u) << 16; return v.f;
}
__device__ __forceinline__ u16 f2bf(float f) {
  u32 x = __builtin_bit_cast(u32, f);
  u32 r = x + 0x7fffu + ((x >> 16) & 1u);
  return (u16)(r >> 16);
}
// 1-op packed f32->bf16 (RNE), T12 primitive
__device__ __forceinline__ u32 cvtpk2(float lo, float hi) {
  u32 r;
  asm("v_cvt_pk_bf16_f32 %0, %1, %2" : "=v"(r) : "v"(lo), "v"(hi));
  return r;
}
__device__ __forceinline__ u16 f2bf_h(float f) { return (u16)(cvtpk2(f, f) & 0xffffu); }
__device__ __forceinline__ bf16x8 ldb8(const u16* p) {
  return *reinterpret_cast<const bf16x8*>(p);
}
__device__ __forceinline__ f32x4 mfma16(bf16x8 a, bf16x8 b, f32x4 c) {
  return __builtin_amdgcn_mfma_f32_16x16x32_bf16(a, b, c, 0, 0, 0);
}
__device__ __forceinline__ float rcp_(float x) { return __builtin_amdgcn_rcpf(x); }
__device__ __forceinline__ float sigm(float x) { return rcp_(1.f + __expf(-x)); }
__device__ __forceinline__ float tanh_(float x) { return 2.f * rcp_(1.f + __expf(-2.f * x)) - 1.f; }

// ---------------- weight prep: f32 -> packed bf16 ----------------
__global__ __launch_bounds__(256) void prep_kernel(
    const float* __restrict__ U_m, const float* __restrict__ W_m,
    const float* __restrict__ U_a, const float* __restrict__ W_a,
    const float* __restrict__ Wd_m, const float* __restrict__ Wd_a,
    const float* __restrict__ eoW,
    u16* __restrict__ UWt_m, u16* __restrict__ UWt_a,
    u16* __restrict__ WdT_m, u16* __restrict__ WdT_a, u16* __restrict__ eoWt)
{
  int idx = blockIdx.x * 256 + threadIdx.x;
  if (idx < 163840) {                          // UWt: [512 cols][160 k]
    int s = idx >= 81920 ? 1 : 0;
    int i = idx - s * 81920;
    int j = i / 160, k = i % 160;
    const float* U = s ? U_a : U_m;
    const float* W = s ? W_a : W_m;
    float v = 0.f;
    if (k < 128) v = U[k * 512 + j];
    else if (k < 144) v = W[(k - 128) * 512 + j];
    (s ? UWt_a : UWt_m)[j * 160 + k] = f2bf(v);
  } else if (idx < 196608) {                   // WdT: [128 cols][128 k]
    int i = idx - 163840;
    int s = i >= 16384 ? 1 : 0;
    i -= s * 16384;
    int j = i >> 7, k = i & 127;
    (s ? WdT_a : WdT_m)[j * 128 + k] = f2bf((s ? Wd_a : Wd_m)[k * 128 + j]);
  } else if (idx < 229376) {                   // eoWt: [128 cols][256 k]
    int i = idx - 196608;
    int j = i >> 8, k = i & 255;
    eoWt[j * 256 + k] = f2bf(eoW[k * 128 + j]);
  }
}

// ---------------- counting sort by e_len ----------------
__global__ void hist_kernel(const int* __restrict__ elen, int* __restrict__ cnt) {
  int e = blockIdx.x * 256 + threadIdx.x;
  int b = min(max(elen[e] - 1, 0), 15);
  atomicAdd(&cnt[b], 1);
}
__global__ void scan_kernel(const int* __restrict__ cnt, int* __restrict__ coff) {
  if (threadIdx.x == 0 && blockIdx.x == 0) {
    int a = 0;
    for (int i = 0; i < 16; ++i) { coff[i] = a; a += cnt[i]; }
  }
}
__global__ void scatter_kernel(const int* __restrict__ elen, int* __restrict__ coff,
                               int* __restrict__ perm) {
  int e = blockIdx.x * 256 + threadIdx.x;
  int b = min(max(elen[e] - 1, 0), 15);
  int pos = atomicAdd(&coff[b], 1);
  perm[pos] = e;
}

// ---------------- T-LSTM over 32 sorted edges; weights pinned in VGPRs ----------------
// A: stride 168 u16; cols 0..127 h(bf16), 128..143 e_t, 144..159 zero.
// C: stride 136 u16; c as bf16 (operand of c@Wd). Exact c in f32 regs.
__global__ __attribute__((amdgpu_waves_per_eu(1, 1))) __launch_bounds__(256)
void lstm_kernel(
    const float* __restrict__ e, const float* __restrict__ dtt,
    const float* __restrict__ b_m, const float* __restrict__ bd_m,
    const float* __restrict__ b_a, const float* __restrict__ bd_a,
    const float* __restrict__ attn,
    const int* __restrict__ elen, const int* __restrict__ perm,
    const u16* __restrict__ UWt_m, const u16* __restrict__ UWt_a,
    const u16* __restrict__ WdT_m, const u16* __restrict__ WdT_a,
    u16* __restrict__ e_out, float* __restrict__ aval_g)
{
  const int bid = blockIdx.x;
  const int sel = bid >> 11;             // 0 = message LSTM, 1 = attention LSTM
  const int edge0 = (bid & 2047) * 32;
  const u16* UWt = sel ? UWt_a : UWt_m;
  const u16* WdT = sel ? WdT_a : WdT_m;
  const float* bg  = sel ? b_a  : b_m;
  const float* bdp = sel ? bd_a : bd_m;

  __shared__ __align__(16) u16 A[32 * 168];
  __shared__ __align__(16) u16 C[32 * 136];
  __shared__ __align__(16) u16 Eo[32 * 136];
  __shared__ float dec_all[16][32];      // [t][row], precomputed once
  __shared__ int rowedge[32], elen_s[32], tmax_s;

  const int tid = threadIdx.x;
  const int w = tid >> 6, lane = tid & 63, l15 = lane & 15, lhi = lane >> 4;
  const int srow = tid >> 3, sp = tid & 7;   // staging row/slot (8 thr/row)

  if (tid < 32) {
    int ed = perm[edge0 + tid];
    rowedge[tid] = ed;
    elen_s[tid] = min(max(elen[ed], 1), 16);
  }
  for (int i = tid; i < 32 * 168; i += 256) A[i] = 0;
  for (int i = tid; i < 32 * 136; i += 256) C[i] = 0;
  __syncthreads();
  if (tid == 0) {
    int mx = 1;
    for (int i = 0; i < 32; ++i) mx = max(mx, elen_s[i]);
    tmax_s = mx;
  }
  // precompute all decays: dec_all[t][row] = 1/log(e + dt[row][t])
  for (int i = tid; i < 512; i += 256) {
    int row = i & 31, t = i >> 5;
    dec_all[t][row] =
        1.f / logf(2.7182818284590452f + dtt[(size_t)rowedge[row] * 16 + t]);
  }
  { // stage e_t for t=0
    float2 e2 = *reinterpret_cast<const float2*>(e + (size_t)rowedge[srow] * 256 + sp * 2);
    *reinterpret_cast<u32*>(&A[srow * 168 + 128 + sp * 2]) = cvtpk2(e2.x, e2.y);
  }

  // ---- persistent weight fragments: loaded ONCE, pinned via opaque asm ----
  bf16x8 BU[5][8];
#pragma unroll
  for (int ks = 0; ks < 5; ++ks)
#pragma unroll
    for (int n = 0; n < 8; ++n)
      BU[ks][n] = ldb8(UWt + (size_t)((n >> 1) * 128 + w * 32 + (n & 1) * 16 + l15) * 160
                       + ks * 32 + lhi * 8);
  bf16x8 BD[4][2];
#pragma unroll
  for (int ks = 0; ks < 4; ++ks)
#pragma unroll
    for (int n = 0; n < 2; ++n)
      BD[ks][n] = ldb8(WdT + (size_t)(w * 32 + n * 16 + l15) * 128 + ks * 32 + lhi * 8);
  // opaque pin: values become asm outputs -> not rematerializable -> stay in regs
#pragma unroll
  for (int ks = 0; ks < 5; ++ks)
#pragma unroll
    for (int n = 0; n < 8; ++n)
      asm volatile("" : "+v"(BU[ks][n]));
#pragma unroll
  for (int ks = 0; ks < 4; ++ks)
#pragma unroll
    for (int n = 0; n < 2; ++n)
      asm volatile("" : "+v"(BD[ks][n]));

  float bgr[8];
#pragma unroll
  for (int n = 0; n < 8; ++n)
    bgr[n] = bg[(n >> 1) * 128 + w * 32 + (n & 1) * 16 + l15];
  float bdr[2];
#pragma unroll
  for (int n = 0; n < 2; ++n) bdr[n] = bdp[w * 32 + n * 16 + l15];

  float cst[2][2][4];
#pragma unroll
  for (int m = 0; m < 2; ++m)
#pragma unroll
    for (int js = 0; js < 2; ++js)
#pragma unroll
      for (int r = 0; r < 4; ++r) cst[m][js][r] = 0.f;
  __syncthreads();
  const int tmax = tmax_s;

  for (int t = 0; t < tmax; ++t) {
    f32x4 acc[2][8];
#pragma unroll
    for (int m = 0; m < 2; ++m)
#pragma unroll
      for (int n = 0; n < 8; ++n) {
        float b = bgr[n];
        f32x4 tmp = {b, b, b, b};
        acc[m][n] = tmp;
      }
    f32x4 accs[2][2];
#pragma unroll
    for (int m = 0; m < 2; ++m)
#pragma unroll
      for (int n = 0; n < 2; ++n) {
        float b = bdr[n];
        f32x4 tmp = {b, b, b, b};
        accs[m][n] = tmp;
      }
#pragma unroll
    for (int ks = 0; ks < 5; ++ks) {
      bf16x8 a0 = ldb8(&A[l15 * 168 + ks * 32 + lhi * 8]);
      bf16x8 a1 = ldb8(&A[(16 + l15) * 168 + ks * 32 + lhi * 8]);
#pragma unroll
      for (int n = 0; n < 8; ++n) {
        acc[0][n] = mfma16(a0, BU[ks][n], acc[0][n]);
        acc[1][n] = mfma16(a1, BU[ks][n], acc[1][n]);
      }
    }
#pragma unroll
    for (int ks = 0; ks < 4; ++ks) {
      bf16x8 c0 = ldb8(&C[l15 * 136 + ks * 32 + lhi * 8]);
      bf16x8 c1 = ldb8(&C[(16 + l15) * 136 + ks * 32 + lhi * 8]);
#pragma unroll
      for (int n = 0; n < 2; ++n) {
        accs[0][n] = mfma16(c0, BD[ks][n], accs[0][n]);
        accs[1][n] = mfma16(c1, BD[ks][n], accs[1][n]);
      }
    }
    __syncthreads();

    // T14 split: issue next e_t global load BEFORE phase B, LDS-write after
    float2 e2n;
    const bool stage_next = (t + 1 < tmax);
    if (stage_next)
      e2n = *reinterpret_cast<const float2*>(
          e + (size_t)rowedge[srow] * 256 + (t + 1) * 16 + sp * 2);

#pragma unroll
    for (int m = 0; m < 2; ++m)
#pragma unroll
      for (int js = 0; js < 2; ++js)
#pragma unroll
        for (int r = 0; r < 4; ++r) {
          const int row = m * 16 + lhi * 4 + r;
          float iv = sigm(acc[m][js][r]);
          float fv = sigm(acc[m][2 + js][r]);
          float ov = sigm(acc[m][4 + js][r]);
          float gv = tanh_(acc[m][6 + js][r]);
          float cs = tanh_(accs[m][js][r]);
          float dec = dec_all[t][row];
          float co = cst[m][js][r];
          float cstar = co + cs * (dec - 1.f);   // c - c_s + c_s*dec
          float cn = fv * cstar + iv * gv;
          float hn = ov * tanh_(cn);
          cst[m][js][r] = cn;
          const int j = w * 32 + js * 16 + l15;
          u16 hb = f2bf_h(hn);
          A[row * 168 + j] = hb;
          C[row * 136 + j] = f2bf_h(cn);
          if (elen_s[row] == t + 1) Eo[row * 136 + j] = hb;
        }
    if (stage_next)
      *reinterpret_cast<u32*>(&A[srow * 168 + 128 + sp * 2]) = cvtpk2(e2n.x, e2n.y);
    __syncthreads();
  }

  if (sel) {   // attention logit: leaky_relu(h . attn_w)
    if (tid < 32) {
      float s = 0.f;
      for (int k = 0; k < 128; ++k) s += bf2f(Eo[tid * 136 + k]) * attn[k];
      aval_g[rowedge[tid]] = s > 0.f ? s : 0.01f * s;
    }
  } else {     // e_out writeback
    uint4 v0 = *reinterpret_cast<const uint4*>(&Eo[srow * 136 + sp * 16]);
    uint4 v1 = *reinterpret_cast<const uint4*>(&Eo[srow * 136 + sp * 16 + 8]);
    u16* dst = e_out + (size_t)rowedge[srow] * 128 + sp * 16;
    *reinterpret_cast<uint4*>(dst) = v0;
    *reinterpret_cast<uint4*>(dst + 8) = v1;
  }
}

// ---------------- per-node: edge GEMM + sparsemax + aggregate + MLP + fc ----------------
__global__ __launch_bounds__(256) void node_kernel(
    const float* __restrict__ nf, const u16* __restrict__ e_out,
    const float* __restrict__ aval_g,
    const float* __restrict__ eoW, const float* __restrict__ eob,
    const float* __restrict__ ndW, const float* __restrict__ ndb,
    const float* __restrict__ fcW, const float* __restrict__ fcb,
    const int* __restrict__ srci, const u16* __restrict__ eoWt,
    float* __restrict__ out)
{
  const int node = blockIdx.x;
  const int tid = threadIdx.x;
  const int ebase = node * 32;
  const int w = tid >> 6, lane = tid & 63, l15 = lane & 15, lhi = lane >> 4;

  __shared__ __align__(16) u16 A2[32 * 264];
  __shared__ __align__(16) u16 Msh[32 * 136];
  __shared__ float selfh[128], aval[32], zsrc[32], zs[32], redf[32], alpha_s[32];
  __shared__ float hagg[128], acts[128], part[2][128];
  __shared__ int redi[32];

  { // stage [h_src | e_out] -> A2[32][256] stride 264 (vectorized)
    const int row = tid >> 3, p = tid & 7;
    const int src = srci[ebase + row];
    const float4* ph = reinterpret_cast<const float4*>(nf + (size_t)src * 128 + p * 16);
    float4 f0 = ph[0], f1 = ph[1], f2 = ph[2], f3 = ph[3];
    uint4 pk0, pk1;
    pk0.x = cvtpk2(f0.x, f0.y); pk0.y = cvtpk2(f0.z, f0.w);
    pk0.z = cvtpk2(f1.x, f1.y); pk0.w = cvtpk2(f1.z, f1.w);
    pk1.x = cvtpk2(f2.x, f2.y); pk1.y = cvtpk2(f2.z, f2.w);
    pk1.z = cvtpk2(f3.x, f3.y); pk1.w = cvtpk2(f3.z, f3.w);
    *reinterpret_cast<uint4*>(&A2[row * 264 + p * 16]) = pk0;
    *reinterpret_cast<uint4*>(&A2[row * 264 + p * 16 + 8]) = pk1;
    const u16* pe = e_out + (size_t)(ebase + row) * 128 + p * 16;
    *reinterpret_cast<uint4*>(&A2[row * 264 + 128 + p * 16]) =
        *reinterpret_cast<const uint4*>(pe);
    *reinterpret_cast<uint4*>(&A2[row * 264 + 128 + p * 16 + 8]) =
        *reinterpret_cast<const uint4*>(pe + 8);
  }
  if (tid < 128) selfh[tid] = nf[(size_t)node * 128 + tid];
  else if (tid < 160) aval[tid - 128] = aval_g[ebase + tid - 128];
  __syncthreads();

  { // edge GEMM: M = relu([h_src | e_out] @ eoW + eob)
    f32x4 eacc[2][2];
    const int j0 = w * 32 + l15, j1 = w * 32 + 16 + l15;
    {
      float v0 = eob[j0], v1 = eob[j1];
      f32x4 t0 = {v0, v0, v0, v0}, t1 = {v1, v1, v1, v1};
      eacc[0][0] = t0; eacc[1][0] = t0;
      eacc[0][1] = t1; eacc[1][1] = t1;
    }
#pragma unroll
    for (int ks = 0; ks < 8; ++ks) {
      bf16x8 a0 = ldb8(&A2[l15 * 264 + ks * 32 + lhi * 8]);
      bf16x8 a1 = ldb8(&A2[(16 + l15) * 264 + ks * 32 + lhi * 8]);
      bf16x8 b0 = ldb8(eoWt + (size_t)j0 * 256 + ks * 32 + lhi * 8);
      bf16x8 b1 = ldb8(eoWt + (size_t)j1 * 256 + ks * 32 + lhi * 8);
      eacc[0][0] = mfma16(a0, b0, eacc[0][0]);
      eacc[1][0] = mfma16(a1, b0, eacc[1][0]);
      eacc[0][1] = mfma16(a0, b1, eacc[0][1]);
      eacc[1][1] = mfma16(a1, b1, eacc[1][1]);
    }
#pragma unroll
    for (int m = 0; m < 2; ++m)
#pragma unroll
      for (int n = 0; n < 2; ++n)
#pragma unroll
        for (int r = 0; r < 4; ++r) {
          const int row = m * 16 + lhi * 4 + r;
          const int j = w * 32 + n * 16 + l15;
          Msh[row * 136 + j] = f2bf_h(fmaxf(eacc[m][n][r], 0.f));
        }
  }
  __syncthreads();

  // sparsemax over aval[32]
  if (tid < 32) {
    float mx = -1e30f;
    for (int jj = 0; jj < 32; ++jj) mx = fmaxf(mx, aval[jj]);
    float z = aval[tid] - mx;
    zsrc[tid] = z;
    int rank = 0;
    for (int jj = 0; jj < 32; ++jj) {
      float zj = aval[jj] - mx;
      rank += (zj > z) || (zj == z && jj < tid);
    }
    zs[rank] = z;
  }
  __syncthreads();
  if (tid < 32) {
    float cum = 0.f;
    for (int s = 0; s <= tid; ++s) cum += zs[s];
    float zst = zs[tid];
    bool isg = (1.f + (float)(tid + 1) * zst) > cum;
    redf[tid] = isg ? zst : 0.f;
    redi[tid] = isg ? (tid + 1) : 0;
  }
  __syncthreads();
  if (tid < 32) {
    int kk = 0; float ss = 0.f;
    for (int jj = 0; jj < 32; ++jj) { kk = max(kk, redi[jj]); ss += redf[jj]; }
    float tau = (ss - 1.f) / (float)kk;
    alpha_s[tid] = fmaxf(0.f, zsrc[tid] - tau);
  }
  __syncthreads();

  // h_agg = sum_d alpha_d * M[d] - self_h_tmp   (split across both half-blocks)
  const int col = tid & 127, half = tid >> 7;
  if (half == 0) {
    float s = 0.f;
    for (int d = 0; d < 32; ++d) s += alpha_s[d] * bf2f(Msh[d * 136 + col]);
    part[0][col] = s;
  } else {
    float st = eob[col];
    for (int k2 = 0; k2 < 128; ++k2) st += selfh[k2] * eoW[k2 * 128 + col];
    part[1][col] = st;
  }
  __syncthreads();
  if (tid < 128) hagg[tid] = part[0][tid] - part[1][tid];
  __syncthreads();

  // node MLP: each column's 256-term dot split across 2 threads
  {
    float Av = half ? 0.f : ndb[col];
    const int k0 = half * 64;
    for (int k2 = k0; k2 < k0 + 64; ++k2) Av += selfh[k2] * ndW[k2 * 128 + col];
    for (int k2 = k0; k2 < k0 + 64; ++k2) Av += hagg[k2] * ndW[(128 + k2) * 128 + col];
    part[half][col] = Av;
  }
  __syncthreads();
  if (tid < 128) acts[tid] = fmaxf(part[0][tid] + part[1][tid], 0.f);
  __syncthreads();

  // fc: 10 classes x 4 lanes each (32 terms/lane, shfl-reduce)
  if (tid < 40) {
    const int cls = tid >> 2, q = tid & 3;
    float o = 0.f;
    for (int k = q * 32; k < q * 32 + 32; ++k) o += acts[k] * fcW[k * 10 + cls];
    o += __shfl_xor(o, 1);
    o += __shfl_xor(o, 2);
    if (q == 0) out[node * 10 + cls] = o + fcb[cls];
  }
}

extern "C" void kernel_launch(void* const* d_in, const int* in_sizes, int n_in,
                              void* d_out, int out_size, void* d_ws, size_t ws_size,
                              hipStream_t stream)
{
  const float* nf   = (const float*)d_in[0];
  const float* e    = (const float*)d_in[1];
  const float* dtt  = (const float*)d_in[2];
  const float* W_m  = (const float*)d_in[3];
  const float* U_m  = (const float*)d_in[4];
  const float* b_m  = (const float*)d_in[5];
  const float* Wd_m = (const float*)d_in[6];
  const float* bd_m = (const float*)d_in[7];
  const float* W_a  = (const float*)d_in[8];
  const float* U_a  = (const float*)d_in[9];
  const float* b_a  = (const float*)d_in[10];
  const float* Wd_a = (const float*)d_in[11];
  const float* bd_a = (const float*)d_in[12];
  const float* attn = (const float*)d_in[13];
  const float* eoW  = (const float*)d_in[14];
  const float* eob  = (const float*)d_in[15];
  const float* ndW  = (const float*)d_in[16];
  const float* ndb  = (const float*)d_in[17];
  const float* fcW  = (const float*)d_in[18];
  const float* fcb  = (const float*)d_in[19];
  const int* elen = (const int*)d_in[20];
  const int* srci = (const int*)d_in[21];

  char* ws = (char*)d_ws;
  u16* UWt_m  = (u16*)(ws + 0);
  u16* UWt_a  = (u16*)(ws + 163840);
  u16* WdT_m  = (u16*)(ws + 327680);
  u16* WdT_a  = (u16*)(ws + 360448);
  u16* eoWt   = (u16*)(ws + 393216);          // ends 458752
  u16* e_out  = (u16*)(ws + 458752);          // 16,777,216 B
  float* aval = (float*)(ws + 17235968);      // 262,144 B
  int* perm   = (int*)(ws + 17498112);        // 262,144 B
  int* cnt    = (int*)(ws + 17760256);        // 64 B
  int* coff   = (int*)(ws + 17760320);        // 64 B

  hipMemsetAsync(cnt, 0, 64, stream);
  prep_kernel<<<896, 256, 0, stream>>>(U_m, W_m, U_a, W_a, Wd_m, Wd_a, eoW,
                                       UWt_m, UWt_a, WdT_m, WdT_a, eoWt);
  hist_kernel<<<EDGES / 256, 256, 0, stream>>>(elen, cnt);
  scan_kernel<<<1, 1, 0, stream>>>(cnt, coff);
  scatter_kernel<<<EDGES / 256, 256, 0, stream>>>(elen, coff, perm);
  lstm_kernel<<<4096, 256, 0, stream>>>(e, dtt, b_m, bd_m, b_a, bd_a, attn,
                                        elen, perm, UWt_m, UWt_a, WdT_m, WdT_a,
                                        e_out, aval);
  node_kernel<<<NDST, 256, 0, stream>>>(nf, e_out, aval, eoW, eob, ndW, ndb,
                                        fcW, fcb, srci, eoWt, (float*)d_out);
}